// Round 1
// 236.616 us; speedup vs baseline: 1.1235x; 1.1235x over previous
//
#include <hip/hip_runtime.h>

#define HW 1024
#define TWO_PI_F 6.28318530717958647692f
#define NSLOT 64   // atomic spreading: 64 slots per accumulator, 5 accumulators

__device__ __forceinline__ float2 cmulf(float2 a, float2 b){
  return make_float2(a.x*b.x - a.y*b.y, a.x*b.y + a.y*b.x);
}
__device__ __forceinline__ float fsqrt(float x){ return __builtin_amdgcn_sqrtf(x); }

// fast |atan2|: caller passes ay = |y| >= 0. Saves the final sign-select.
__device__ __forceinline__ float fast_atan2_abs(float ay, float x){
  float ax = fabsf(x);
  float mx = fmaxf(ax, ay), mn = fminf(ax, ay);
  float a  = mn * __builtin_amdgcn_rcpf(fmaxf(mx, 1e-37f));
  float s  = a * a;
  float r  = ((((0.0208351f*s - 0.085133f)*s + 0.180141f)*s - 0.3302995f)*s
              + 0.999866f) * a;
  r = (ay > ax) ? 1.57079632679f - r : r;
  return (x < 0.f) ? 3.14159265359f - r : r;
}

// 256-thread block reduction (4 waves of 64), float
__device__ __forceinline__ float block_reduce_add_f(float v, float* sc){
  int tid = threadIdx.x;
  #pragma unroll
  for (int o = 32; o > 0; o >>= 1) v += __shfl_down(v, o, 64);
  __syncthreads();
  if ((tid & 63) == 0) sc[tid >> 6] = v;
  __syncthreads();
  return sc[0] + sc[1] + sc[2] + sc[3];
}

// merged setup: zero accumulators + twiddle table (one launch)
__global__ void setup_kernel(double* acc, float2* twg){
  int i = threadIdx.x + blockIdx.x * 256;   // grid 2 x 256 -> 0..511
  if (i < 5 * NSLOT) acc[i] = 0.0;
  if (i < 512){
    float s, c; sincosf(-TWO_PI_F * (float)i * (1.f/1024.f), &s, &c);
    twg[i] = make_float2(c, s);
  }
}

// ---------------------------------------------------------------------------
// Spatial half: 32x32 tile/block, 4 px/thread, one dispatch.
// R14: LDS overlay (smkf dead after mrow build -> reuse for pmg/tmg):
//      26.6 KB -> 22.5 KB => 7 blocks/CU (was 6). Interior blocks stage with
//      aligned float4 loads (no per-element bounds checks). sp/st stride 44
//      (16B-aligned rows, window x0-4..x0+35).
// ---------------------------------------------------------------------------
__global__ __launch_bounds__(256)
void spatial_kernel(const float* __restrict__ pred, const float* __restrict__ targ,
                    const float* __restrict__ mask, double* __restrict__ acc){
  __shared__ float sp[36*44];
  __shared__ float st[36*44];
  __shared__ float ov[2*34*35];            // union: smkf[38*41] (1558) / pmg+tmg (2380)
  __shared__ unsigned long long mrow[38];
  __shared__ float sc[4];
  float* const smkf = ov;
  float* const pmg  = ov;
  float* const tmg  = ov + 34*35;

  const int tid = threadIdx.x;
  const int x0 = blockIdx.x << 5, y0 = blockIdx.y << 5;
  const int z = blockIdx.z;
  const size_t ib = (size_t)z * ((size_t)HW * HW);
  const bool interior = ((unsigned)(blockIdx.x - 1) < 30u) &&
                        ((unsigned)(blockIdx.y - 1) < 30u);

  if (interior){
    const float* pb = pred + ib;
    const float* tb = targ + ib;
    for (int i = tid; i < 360; i += 256){        // 36 rows x 10 float4 (40 cols)
      int a = i / 10, b = i % 10;
      size_t off = (size_t)(y0 - 2 + a) * HW + (x0 - 4 + 4*b);
      float4 pv = *(const float4*)(pb + off);
      float4 tv = *(const float4*)(tb + off);
      int o = a*44 + 4*b;
      sp[o]=pv.x; sp[o+1]=pv.y; sp[o+2]=pv.z; sp[o+3]=pv.w;
      st[o]=tv.x; st[o+1]=tv.y; st[o+2]=tv.z; st[o+3]=tv.w;
    }
    const float* mb = mask + ib;
    for (int i = tid; i < 380; i += 256){        // 38 rows x 10 float4
      int a = i / 10, b = i % 10;
      size_t off = (size_t)(y0 - 3 + a) * HW + (x0 - 4 + 4*b);
      float4 v = *(const float4*)(mb + off);
      int o = a*41 + 4*b;
      smkf[o]=v.x; smkf[o+1]=v.y; smkf[o+2]=v.z; smkf[o+3]=v.w;
    }
  } else {
    for (int i = tid; i < 1296; i += 256){
      int a = i / 36, b = i % 36;
      int gy = y0 - 2 + a, gx = x0 - 2 + b;
      float pv = 0.f, tv = 0.f;
      if ((unsigned)gy < HW && (unsigned)gx < HW){
        size_t idx = ib + (size_t)gy * HW + gx;
        pv = pred[idx]; tv = targ[idx];
      }
      sp[a*44 + b + 2] = pv; st[a*44 + b + 2] = tv;
    }
    for (int i = tid; i < 1444; i += 256){
      int a = i / 38, b = i % 38;
      int gy = y0 - 3 + a, gx = x0 - 3 + b;
      float v = 0.f;
      if ((unsigned)gy < HW && (unsigned)gx < HW) v = mask[ib + (size_t)gy * HW + gx];
      smkf[a*41 + b + 1] = v;
    }
  }
  __syncthreads();

  if (tid < 38){
    unsigned long long w = 0ull;
    #pragma unroll
    for (int x = 0; x < 38; x++)
      w |= (smkf[tid*41 + 1 + x] > 0.5f) ? (1ull << x) : 0ull;
    mrow[tid] = w;
  }
  __syncthreads();                              // smkf dead below; ov reused

  for (int i = tid; i < 1156; i += 256){
    int iy = i / 34, ix = i % 34;
    int gy = y0 - 1 + iy, gx = x0 - 1 + ix;
    float pv = 0.f, tv = 0.f;
    if ((unsigned)gy < HW && (unsigned)gx < HW){
      int o = iy*44 + ix + 2;
      float a00=sp[o], a01=sp[o+1], a02=sp[o+2];
      float a10=sp[o+44],           a12=sp[o+46];
      float a20=sp[o+88], a21=sp[o+89], a22=sp[o+90];
      float gxp = (a02 + 2.f*a12 + a22) - (a00 + 2.f*a10 + a20);
      float gyp = (a20 + 2.f*a21 + a22) - (a00 + 2.f*a01 + a02);
      pv = fsqrt(gxp*gxp + gyp*gyp + 1e-8f);
      float b00=st[o], b01=st[o+1], b02=st[o+2];
      float b10=st[o+44],           b12=st[o+46];
      float b20=st[o+88], b21=st[o+89], b22=st[o+90];
      float gxt = (b02 + 2.f*b12 + b22) - (b00 + 2.f*b10 + b20);
      float gyt = (b20 + 2.f*b21 + b22) - (b00 + 2.f*b01 + b02);
      tv = fsqrt(gxt*gxt + gyt*gyt + 1e-8f);
    }
    pmg[iy*35+ix] = pv; tmg[iy*35+ix] = tv;
  }
  __syncthreads();

  const int ty = tid >> 5, tx = tid & 31;
  const int r0 = ty << 2;

  int c1[10], c2[10], c3[10];
  #pragma unroll
  for (int j = 0; j < 10; j++){
    unsigned w = (unsigned)(mrow[r0 + j] >> tx);
    c3[j] = __popc(w & 0x7Fu);
    c2[j] = __popc((w >> 1) & 0x1Fu);
    c1[j] = __popc((w >> 2) & 0x7u);
  }

  float P[3][3], Q[3][3], A[3][3], B[3][3];
  #pragma unroll
  for (int rr = 0; rr < 3; rr++)
    #pragma unroll
    for (int cc = 0; cc < 3; cc++){
      P[rr][cc] = sp[(r0+1+rr)*44 + tx+3+cc];
      Q[rr][cc] = st[(r0+1+rr)*44 + tx+3+cc];
      A[rr][cc] = pmg[(r0+rr)*35 + tx+cc];
      B[rr][cc] = tmg[(r0+rr)*35 + tx+cc];
    }

  float accg = 0.f, accs = 0.f, accl = 0.f;
  #pragma unroll
  for (int k = 0; k < 4; k++){
    if (k){
      #pragma unroll
      for (int cc = 0; cc < 3; cc++){
        P[0][cc]=P[1][cc]; P[1][cc]=P[2][cc]; P[2][cc]=sp[(r0+k+3)*44 + tx+3+cc];
        Q[0][cc]=Q[1][cc]; Q[1][cc]=Q[2][cc]; Q[2][cc]=st[(r0+k+3)*44 + tx+3+cc];
        A[0][cc]=A[1][cc]; A[1][cc]=A[2][cc]; A[2][cc]=pmg[(r0+k+2)*35 + tx+cc];
        B[0][cc]=B[1][cc]; B[1][cc]=B[2][cc]; B[2][cc]=tmg[(r0+k+2)*35 + tx+cc];
      }
    }
    float gxp = (P[0][2]+2.f*P[1][2]+P[2][2]) - (P[0][0]+2.f*P[1][0]+P[2][0]);
    float gyp = (P[2][0]+2.f*P[2][1]+P[2][2]) - (P[0][0]+2.f*P[0][1]+P[0][2]);
    float cvp = 4.f*P[1][1] - P[0][1] - P[1][0] - P[1][2] - P[2][1];
    float gxt = (Q[0][2]+2.f*Q[1][2]+Q[2][2]) - (Q[0][0]+2.f*Q[1][0]+Q[2][0]);
    float gyt = (Q[2][0]+2.f*Q[2][1]+Q[2][2]) - (Q[0][0]+2.f*Q[0][1]+Q[0][2]);
    float cvt = 4.f*Q[1][1] - Q[0][1] - Q[1][0] - Q[1][2] - Q[2][1];

    float sd = fabsf(A[1][1] - B[1][1]);
    float x1 = gxp + 1e-8f, y1 = gyp;
    float x2 = gxt + 1e-8f, y2 = gyt;
    float dd = fast_atan2_abs(fabsf(y1*x2 - x1*y2), x1*x2 + y1*y2);
    float cd = fabsf(cvp - cvt);

    int s1 = c1[k+2]+c1[k+3]+c1[k+4];
    int s2 = c2[k+1]+c2[k+2]+c2[k+3]+c2[k+4]+c2[k+5];
    int s3 = c3[k]+c3[k+1]+c3[k+2]+c3[k+3]+c3[k+4]+c3[k+5]+c3[k+6];
    float w1 = ((unsigned)(s1 - 1) <  8u) ? 1.f : 0.f;
    float w2 = ((unsigned)(s2 - 1) < 24u) ? 1.f : 0.f;
    float w3 = ((unsigned)(s3 - 1) < 48u) ? 1.f : 0.f;

    accg += (sd + dd) * (w1 + 0.5f*(w2 + w3)) + cd * (2.f*w1 + w2 + w3);

    float s9 = 0.f, s9q = 0.f;
    #pragma unroll
    for (int rr = 0; rr < 3; rr++)
      #pragma unroll
      for (int cc = 0; cc < 3; cc++){ s9 += P[rr][cc]; s9q += P[rr][cc]*P[rr][cc]; }
    float lm = s9 * (1.f/9.f), lq = s9q * (1.f/9.f);
    accs += fsqrt(fmaxf(lq - lm*lm, 1e-8f)) * w1;

    float psx = (A[0][2]+2.f*A[1][2]+A[2][2]) - (A[0][0]+2.f*A[1][0]+A[2][0]);
    float psy = (A[2][0]+2.f*A[2][1]+A[2][2]) - (A[0][0]+2.f*A[0][1]+A[0][2]);
    float pch = fsqrt(psx*psx + psy*psy + 1e-8f);
    float tsx = (B[0][2]+2.f*B[1][2]+B[2][2]) - (B[0][0]+2.f*B[1][0]+B[2][0]);
    float tsy = (B[2][0]+2.f*B[2][1]+B[2][2]) - (B[0][0]+2.f*B[0][1]+B[0][2]);
    float tch = fsqrt(tsx*tsx + tsy*tsy + 1e-8f);
    accl += fabsf(pch - tch) * w1;
  }

  float g  = block_reduce_add_f(accg, sc);
  float sm = block_reduce_add_f(accs, sc);
  float sl = block_reduce_add_f(accl, sc);
  if (tid == 0){
    int slot = (blockIdx.x + blockIdx.y * 7 + z * 13) & (NSLOT - 1);
    atomicAdd(&acc[0*NSLOT + slot], (double)g);
    atomicAdd(&acc[1*NSLOT + slot], (double)sm);
    atomicAdd(&acc[2*NSLOT + slot], (double)sl);
  }
}

// ---------------------------------------------------------------------------
// Lane-xor exchange (HW-verified R13): DPP for h=1,2,8; ds_swizzle h=4,16;
// bpermute h=32.
// ---------------------------------------------------------------------------
__device__ __forceinline__ float lane_xor(float x, int h, int lane){
  int xi = __float_as_int(x);
  int r;
  if (h == 1)       r = __builtin_amdgcn_update_dpp(xi, xi, 0xB1, 0xF, 0xF, true);
  else if (h == 2)  r = __builtin_amdgcn_update_dpp(xi, xi, 0x4E, 0xF, 0xF, true);
  else if (h == 8)  r = __builtin_amdgcn_update_dpp(xi, xi, 0x128, 0xF, 0xF, true);
  else if (h == 4)  r = __builtin_amdgcn_ds_swizzle(xi, 0x101F);  // xor4
  else if (h == 16) r = __builtin_amdgcn_ds_swizzle(xi, 0x401F);  // xor16
  else              r = __builtin_amdgcn_ds_bpermute((lane ^ 32) << 2, xi);
  return __int_as_float(r);
}

// ---------------------------------------------------------------------------
// Wave-level 1024-pt FFT: 64 (cross-lane) x 16 (in-register).
// R14: twiddle-before-exchange butterfly. Each lane computes t = w_eff * v
// (w_eff = up ? w : 1), exchanges t, result = fma(sgn, t, partner_t).
// Bit-identical math (w*high computed once instead of twice), 8 VALU/butterfly
// instead of 14. Tail twiddles via log-depth power ladder (no 15-deep chain).
// ---------------------------------------------------------------------------
#define FC 0.70710678118654752f
#define FC1 0.92387953251128676f
#define FS1 0.38268343236508977f

__device__ __forceinline__ void bfly(float2& a, float2& b){
  float tx = b.x, ty = b.y;
  b.x = a.x - tx; b.y = a.y - ty;
  a.x += tx;      a.y += ty;
}
__device__ __forceinline__ void cmul_c(float2& b, float wr, float wi){
  float tx = wr*b.x - wi*b.y, ty = wr*b.y + wi*b.x;
  b.x = tx; b.y = ty;
}
__device__ __forceinline__ void rotmi(float2& b){   // b *= -i
  float t = b.x; b.x = b.y; b.y = -t;
}

__device__ __forceinline__ void fft16_reg(float2* v){
  float2 y[16];
  y[0]=v[0];  y[1]=v[8];  y[2]=v[4];  y[3]=v[12];
  y[4]=v[2];  y[5]=v[10]; y[6]=v[6];  y[7]=v[14];
  y[8]=v[1];  y[9]=v[9];  y[10]=v[5]; y[11]=v[13];
  y[12]=v[3]; y[13]=v[11];y[14]=v[7]; y[15]=v[15];
  #pragma unroll
  for (int g = 0; g < 8; g++) bfly(y[2*g], y[2*g+1]);
  #pragma unroll
  for (int g = 0; g < 4; g++){
    int b = 4*g;
    bfly(y[b], y[b+2]);
    rotmi(y[b+3]); bfly(y[b+1], y[b+3]);
  }
  #pragma unroll
  for (int g = 0; g < 2; g++){
    int b = 8*g;
    bfly(y[b], y[b+4]);
    cmul_c(y[b+5],  FC, -FC); bfly(y[b+1], y[b+5]);
    rotmi(y[b+6]);            bfly(y[b+2], y[b+6]);
    cmul_c(y[b+7], -FC, -FC); bfly(y[b+3], y[b+7]);
  }
  bfly(y[0], y[8]);
  cmul_c(y[9],   FC1, -FS1); bfly(y[1], y[9]);
  cmul_c(y[10],  FC,  -FC);  bfly(y[2], y[10]);
  cmul_c(y[11],  FS1, -FC1); bfly(y[3], y[11]);
  rotmi(y[12]);              bfly(y[4], y[12]);
  cmul_c(y[13], -FS1, -FC1); bfly(y[5], y[13]);
  cmul_c(y[14], -FC,  -FC);  bfly(y[6], y[14]);
  cmul_c(y[15], -FC1, -FS1); bfly(y[7], y[15]);
  #pragma unroll
  for (int j = 0; j < 16; j++) v[j] = y[j];
}

__device__ __forceinline__ void fft1024_wave(float2* v, int lane,
                                             const float2* __restrict__ twg){
  // stage 0 (w = 1 for all lanes): t = v; exchange; v = partner_t + sgn*t
  {
    const float sgn = (lane & 1) ? -1.f : 1.f;
    #pragma unroll
    for (int j = 0; j < 16; j++){
      float ox = lane_xor(v[j].x, 1, lane);
      float oy = lane_xor(v[j].y, 1, lane);
      v[j].x = fmaf(sgn, v[j].x, ox);
      v[j].y = fmaf(sgn, v[j].y, oy);
    }
  }
  #pragma unroll
  for (int s = 1; s < 6; s++){
    const int h = 1 << s;
    const bool up = (lane & h) != 0;
    const float2 w = twg[(lane & (h - 1)) << (9 - s)];
    const float ewx = up ? w.x : 1.f;
    const float ewy = up ? w.y : 0.f;
    const float sgn = up ? -1.f : 1.f;
    #pragma unroll
    for (int j = 0; j < 16; j++){
      float tx = ewx*v[j].x - ewy*v[j].y;
      float ty = ewx*v[j].y + ewy*v[j].x;
      float ox = lane_xor(tx, h, lane);
      float oy = lane_xor(ty, h, lane);
      v[j].x = fmaf(sgn, tx, ox);
      v[j].y = fmaf(sgn, ty, oy);
    }
  }
  // per-slot twiddle: v[j] *= w^j, w = twg[lane]; log-depth powers
  float2 w1 = twg[lane];
  float2 w2 = cmulf(w1, w1);
  float2 w3 = cmulf(w2, w1);
  float2 w4 = cmulf(w2, w2);
  float2 w5 = cmulf(w3, w2);
  float2 w6 = cmulf(w3, w3);
  float2 w7 = cmulf(w4, w3);
  float2 w8 = cmulf(w4, w4);
  v[1]  = cmulf(v[1],  w1);
  v[2]  = cmulf(v[2],  w2);
  v[3]  = cmulf(v[3],  w3);
  v[4]  = cmulf(v[4],  w4);
  v[5]  = cmulf(v[5],  w5);
  v[6]  = cmulf(v[6],  w6);
  v[7]  = cmulf(v[7],  w7);
  v[8]  = cmulf(v[8],  w8);
  v[9]  = cmulf(cmulf(v[9],  w8), w1);
  v[10] = cmulf(cmulf(v[10], w8), w2);
  v[11] = cmulf(cmulf(v[11], w8), w3);
  v[12] = cmulf(cmulf(v[12], w8), w4);
  v[13] = cmulf(cmulf(v[13], w8), w5);
  v[14] = cmulf(cmulf(v[14], w8), w6);
  v[15] = cmulf(cmulf(v[15], w8), w7);
  fft16_reg(v);
}

// ---------------------------------------------------------------------------
// FFT pass 1 + tiled transpose: Zt layout [y>>3][k][y&7] (fp32 float2).
// R14: 2-phase transpose (tile[8] instead of tile[4]) -> 4 barriers not 8.
// LDS 36.9 KB still allows 4 blocks/CU (grid is 4 blocks/CU; VGPRs bind first).
// ---------------------------------------------------------------------------
__global__ __launch_bounds__(512)
void fft_rows_t_kernel(const float* __restrict__ pred, const float* __restrict__ targ,
                       float2* __restrict__ Zt, const float2* __restrict__ twg){
  __shared__ float2 tile[8][64][9];
  const int tid = threadIdx.x;
  const int lane = tid & 63;
  const int w = tid >> 6;
  const int y0 = blockIdx.x << 3;
  const size_t ibase = ((size_t)blockIdx.y * HW + (y0 + w)) * HW;
  const int rb = __brev(lane) >> 26;
  const float4* p4 = (const float4*)(pred + ibase);
  const float4* t4 = (const float4*)(targ + ibase);
  float2 v[16];
  #pragma unroll
  for (int m = 0; m < 4; m++){
    float4 a = p4[4*rb + m];
    float4 b = t4[4*rb + m];
    v[4*m+0] = make_float2(a.x, b.x);
    v[4*m+1] = make_float2(a.y, b.y);
    v[4*m+2] = make_float2(a.z, b.z);
    v[4*m+3] = make_float2(a.w, b.w);
  }
  fft1024_wave(v, lane, twg);
  float2* zb = Zt + (size_t)blockIdx.y * HW * HW + (size_t)blockIdx.x * 8192;
  const int yl = tid & 7, kl = tid >> 3;
  #pragma unroll
  for (int jb = 0; jb < 2; jb++){
    __syncthreads();
    #pragma unroll
    for (int jj = 0; jj < 8; jj++) tile[jj][lane][w] = v[8*jb + jj];
    __syncthreads();
    #pragma unroll
    for (int jj = 0; jj < 8; jj++){
      int k = ((jb << 3) + jj) * 64 + kl;
      zb[k * 8 + yl] = tile[jj][kl][yl];     // contiguous across the block
    }
  }
}

// ---------------------------------------------------------------------------
// FFT pass 2 + reduce: one FFT per wave, Hermitian partner via natural-order
// LDS. Reads the tiled Zt: lane's 16-y chunk = two 64-B contiguous segments.
// ---------------------------------------------------------------------------
__device__ __forceinline__ void freq_contrib(float2 Zk, float2 Zm, int k1, int k2,
                                             float& ms, float& ps){
  int di = k1 - 512, dj = k2 - 512;
  if (di*di + dj*dj < 94372) return;         // dist > 307.2  <=>  r2 >= 94372
  float pr = 0.5f*(Zk.x + Zm.x);
  float pi = 0.5f*(Zk.y - Zm.y);
  float tr = 0.5f*(Zk.y + Zm.y);
  float ti = 0.5f*(Zm.x - Zk.x);
  float p2 = pr*pr + pi*pi;
  float t2 = tr*tr + ti*ti;
  ms += p2 + t2 - 2.f*fsqrt(p2*t2);
  float re = pr*tr + pi*ti;
  float im = pi*tr - pr*ti;
  float pd = fast_atan2_abs(fabsf(im), re);  // squared below; sign irrelevant
  ps += pd*pd;
}

__global__ __launch_bounds__(256)
void fft_cols2_kernel(const float2* __restrict__ Z, const float2* __restrict__ twg,
                      double* __restrict__ acc){
  __shared__ float2 ex[4][1024];            // per-wave natural-order spectrum
  const int lane = threadIdx.x & 63;
  const int w = threadIdx.x >> 6;           // 0..3
  const int p = 2 * blockIdx.x + (w >> 1);  // pair index, 0..512 valid
  const bool valid = (p <= 512);
  const int r = (w & 1) ? ((1024 - p) & 1023) : p;   // this wave's Zt row (k)
  const float2* base = Z + (size_t)blockIdx.y * HW * HW;
  const int rb = __brev(lane) >> 26;

  float2 v[16];
  if (valid){
    const float4* f4 = (const float4*)base;
    #pragma unroll
    for (int s = 0; s < 2; s++){
      size_t o = (size_t)(2*rb + s) * 4096 + (size_t)r * 4;  // float4 units
      #pragma unroll
      for (int q = 0; q < 4; q++){
        float4 x = f4[o + q];
        v[8*s + 2*q]     = make_float2(x.x, x.y);
        v[8*s + 2*q + 1] = make_float2(x.z, x.w);
      }
    }
    fft1024_wave(v, lane, twg);
    #pragma unroll
    for (int j = 0; j < 16; j++) ex[w][lane + (j << 6)] = v[j];
  }
  __syncthreads();
  if (!valid) return;
  const bool self = (p == 0) || (p == 512);
  if ((w & 1) && self) return;              // duplicate row: LDS written, no contribs

  const float2* pb = ex[w ^ 1];             // partner spectrum, natural order
  float ms = 0.f, ps = 0.f;
  #pragma unroll
  for (int j = 0; j < 16; j++){
    int k = lane + (j << 6);
    float2 zm = pb[(1024 - k) & 1023];      // Z_partner(-k)
    freq_contrib(v[j], zm, k, r, ms, ps);
  }
  #pragma unroll
  for (int o = 32; o > 0; o >>= 1){
    ms += __shfl_down(ms, o, 64);
    ps += __shfl_down(ps, o, 64);
  }
  if (lane == 0){
    int slot = (r + blockIdx.y * 11) & (NSLOT - 1);
    atomicAdd(&acc[3*NSLOT + slot], (double)ms);
    atomicAdd(&acc[4*NSLOT + slot], (double)ps);
  }
}

// ---------------------------------------------------------------------------
__global__ void finalize_kernel(const double* __restrict__ acc, float* __restrict__ out){
  const int t = threadIdx.x;   // 64 threads
  double v[5];
  #pragma unroll
  for (int s = 0; s < 5; s++) v[s] = acc[s*NSLOT + t];
  #pragma unroll
  for (int o = 32; o > 0; o >>= 1)
    #pragma unroll
    for (int s = 0; s < 5; s++) v[s] += __shfl_down(v[s], o, 64);
  if (t == 0){
    const double inv = 1.0 / 8388608.0;      // mean over 8*1024*1024
    double grad   = v[0] * inv / 3.0;        // / len(bms)
    double smooth = v[1] * inv;
    double slope  = v[2] * inv;
    double freq   = (v[3] + 2.0 * v[4]) * inv;
    double total  = 2.0*grad + 1.5*freq + 3.0*smooth + 2.0*slope;
    out[0] = (float)total;
    out[1] = (float)grad;
    out[2] = (float)freq;
    out[3] = (float)smooth;
    out[4] = (float)slope;
  }
}

extern "C" void kernel_launch(void* const* d_in, const int* in_sizes, int n_in,
                              void* d_out, int out_size, void* d_ws, size_t ws_size,
                              hipStream_t stream){
  const float* pred = (const float*)d_in[0];
  const float* targ = (const float*)d_in[1];
  const float* mask = (const float*)d_in[2];
  double* acc  = (double*)d_ws;                         // [0, 2560)
  float2* twg  = (float2*)((char*)d_ws + 4096);         // [4096, 8192)
  float2* Z    = (float2*)((char*)d_ws + 8192);         // 8 x 8 MiB fp32 images
  // ws_size ~256 MiB (measured R9) — 64 MiB Z fits with margin.

  setup_kernel<<<2, 256, 0, stream>>>(acc, twg);
  spatial_kernel<<<dim3(32, 32, 8), 256, 0, stream>>>(pred, targ, mask, acc);
  fft_rows_t_kernel<<<dim3(128, 8), 512, 0, stream>>>(pred, targ, Z, twg);
  fft_cols2_kernel<<<dim3(257, 8), 256, 0, stream>>>(Z, twg, acc);
  finalize_kernel<<<1, 64, 0, stream>>>(acc, (float*)d_out);
}

// Round 2
// 235.340 us; speedup vs baseline: 1.1295x; 1.0054x over previous
//
#include <hip/hip_runtime.h>

#define HW 1024
#define TWO_PI_F 6.28318530717958647692f
#define NSLOT 64   // atomic spreading: 64 slots per accumulator, 5 accumulators

__device__ __forceinline__ float2 cmulf(float2 a, float2 b){
  return make_float2(a.x*b.x - a.y*b.y, a.x*b.y + a.y*b.x);
}
__device__ __forceinline__ float fsqrt(float x){ return __builtin_amdgcn_sqrtf(x); }

// fast |atan2|: caller passes ay = |y| >= 0. Saves the final sign-select.
__device__ __forceinline__ float fast_atan2_abs(float ay, float x){
  float ax = fabsf(x);
  float mx = fmaxf(ax, ay), mn = fminf(ax, ay);
  float a  = mn * __builtin_amdgcn_rcpf(fmaxf(mx, 1e-37f));
  float s  = a * a;
  float r  = ((((0.0208351f*s - 0.085133f)*s + 0.180141f)*s - 0.3302995f)*s
              + 0.999866f) * a;
  r = (ay > ax) ? 1.57079632679f - r : r;
  return (x < 0.f) ? 3.14159265359f - r : r;
}

// 256-thread block reduction (4 waves of 64), float
__device__ __forceinline__ float block_reduce_add_f(float v, float* sc){
  int tid = threadIdx.x;
  #pragma unroll
  for (int o = 32; o > 0; o >>= 1) v += __shfl_down(v, o, 64);
  __syncthreads();
  if ((tid & 63) == 0) sc[tid >> 6] = v;
  __syncthreads();
  return sc[0] + sc[1] + sc[2] + sc[3];
}

// merged setup: zero accumulators + twiddle table (one launch)
__global__ void setup_kernel(double* acc, float2* twg){
  int i = threadIdx.x + blockIdx.x * 256;   // grid 2 x 256 -> 0..511
  if (i < 5 * NSLOT) acc[i] = 0.0;
  if (i < 512){
    float s, c; sincosf(-TWO_PI_F * (float)i * (1.f/1024.f), &s, &c);
    twg[i] = make_float2(c, s);
  }
}

// ---------------------------------------------------------------------------
// Spatial half: 32x32 tile/block, 4 px/thread, one dispatch.
// R15: __launch_bounds__(256,4). R14's VGPR_Count=40 proved the compiler was
// rematerializing the >=66-reg live set (P/Q/A/B=36, c1/c2/c3=30) from LDS,
// ~3x instruction bloat. Pin 4 waves/EU (= the 50% occupancy we measure
// anyway) -> VGPR cap 128 -> keep state in registers.
// ---------------------------------------------------------------------------
__global__ __launch_bounds__(256, 4)
void spatial_kernel(const float* __restrict__ pred, const float* __restrict__ targ,
                    const float* __restrict__ mask, double* __restrict__ acc){
  __shared__ float sp[36*44];
  __shared__ float st[36*44];
  __shared__ float ov[2*34*35];            // union: smkf[38*41] (1558) / pmg+tmg (2380)
  __shared__ unsigned long long mrow[38];
  __shared__ float sc[4];
  float* const smkf = ov;
  float* const pmg  = ov;
  float* const tmg  = ov + 34*35;

  const int tid = threadIdx.x;
  const int x0 = blockIdx.x << 5, y0 = blockIdx.y << 5;
  const int z = blockIdx.z;
  const size_t ib = (size_t)z * ((size_t)HW * HW);
  const bool interior = ((unsigned)(blockIdx.x - 1) < 30u) &&
                        ((unsigned)(blockIdx.y - 1) < 30u);

  if (interior){
    const float* pb = pred + ib;
    const float* tb = targ + ib;
    for (int i = tid; i < 360; i += 256){        // 36 rows x 10 float4 (40 cols)
      int a = i / 10, b = i % 10;
      size_t off = (size_t)(y0 - 2 + a) * HW + (x0 - 4 + 4*b);
      float4 pv = *(const float4*)(pb + off);
      float4 tv = *(const float4*)(tb + off);
      int o = a*44 + 4*b;
      sp[o]=pv.x; sp[o+1]=pv.y; sp[o+2]=pv.z; sp[o+3]=pv.w;
      st[o]=tv.x; st[o+1]=tv.y; st[o+2]=tv.z; st[o+3]=tv.w;
    }
    const float* mb = mask + ib;
    for (int i = tid; i < 380; i += 256){        // 38 rows x 10 float4
      int a = i / 10, b = i % 10;
      size_t off = (size_t)(y0 - 3 + a) * HW + (x0 - 4 + 4*b);
      float4 v = *(const float4*)(mb + off);
      int o = a*41 + 4*b;
      smkf[o]=v.x; smkf[o+1]=v.y; smkf[o+2]=v.z; smkf[o+3]=v.w;
    }
  } else {
    for (int i = tid; i < 1296; i += 256){
      int a = i / 36, b = i % 36;
      int gy = y0 - 2 + a, gx = x0 - 2 + b;
      float pv = 0.f, tv = 0.f;
      if ((unsigned)gy < HW && (unsigned)gx < HW){
        size_t idx = ib + (size_t)gy * HW + gx;
        pv = pred[idx]; tv = targ[idx];
      }
      sp[a*44 + b + 2] = pv; st[a*44 + b + 2] = tv;
    }
    for (int i = tid; i < 1444; i += 256){
      int a = i / 38, b = i % 38;
      int gy = y0 - 3 + a, gx = x0 - 3 + b;
      float v = 0.f;
      if ((unsigned)gy < HW && (unsigned)gx < HW) v = mask[ib + (size_t)gy * HW + gx];
      smkf[a*41 + b + 1] = v;
    }
  }
  __syncthreads();

  if (tid < 38){
    unsigned long long w = 0ull;
    #pragma unroll
    for (int x = 0; x < 38; x++)
      w |= (smkf[tid*41 + 1 + x] > 0.5f) ? (1ull << x) : 0ull;
    mrow[tid] = w;
  }
  __syncthreads();                              // smkf dead below; ov reused

  if (interior){
    for (int i = tid; i < 1156; i += 256){      // no bounds checks: always in-range
      int iy = i / 34, ix = i % 34;
      int o = iy*44 + ix + 2;
      float a00=sp[o], a01=sp[o+1], a02=sp[o+2];
      float a10=sp[o+44],           a12=sp[o+46];
      float a20=sp[o+88], a21=sp[o+89], a22=sp[o+90];
      float gxp = (a02 + 2.f*a12 + a22) - (a00 + 2.f*a10 + a20);
      float gyp = (a20 + 2.f*a21 + a22) - (a00 + 2.f*a01 + a02);
      float b00=st[o], b01=st[o+1], b02=st[o+2];
      float b10=st[o+44],           b12=st[o+46];
      float b20=st[o+88], b21=st[o+89], b22=st[o+90];
      float gxt = (b02 + 2.f*b12 + b22) - (b00 + 2.f*b10 + b20);
      float gyt = (b20 + 2.f*b21 + b22) - (b00 + 2.f*b01 + b02);
      pmg[iy*35+ix] = fsqrt(gxp*gxp + gyp*gyp + 1e-8f);
      tmg[iy*35+ix] = fsqrt(gxt*gxt + gyt*gyt + 1e-8f);
    }
  } else {
    for (int i = tid; i < 1156; i += 256){
      int iy = i / 34, ix = i % 34;
      int gy = y0 - 1 + iy, gx = x0 - 1 + ix;
      float pv = 0.f, tv = 0.f;
      if ((unsigned)gy < HW && (unsigned)gx < HW){
        int o = iy*44 + ix + 2;
        float a00=sp[o], a01=sp[o+1], a02=sp[o+2];
        float a10=sp[o+44],           a12=sp[o+46];
        float a20=sp[o+88], a21=sp[o+89], a22=sp[o+90];
        float gxp = (a02 + 2.f*a12 + a22) - (a00 + 2.f*a10 + a20);
        float gyp = (a20 + 2.f*a21 + a22) - (a00 + 2.f*a01 + a02);
        pv = fsqrt(gxp*gxp + gyp*gyp + 1e-8f);
        float b00=st[o], b01=st[o+1], b02=st[o+2];
        float b10=st[o+44],           b12=st[o+46];
        float b20=st[o+88], b21=st[o+89], b22=st[o+90];
        float gxt = (b02 + 2.f*b12 + b22) - (b00 + 2.f*b10 + b20);
        float gyt = (b20 + 2.f*b21 + b22) - (b00 + 2.f*b01 + b02);
        tv = fsqrt(gxt*gxt + gyt*gyt + 1e-8f);
      }
      pmg[iy*35+ix] = pv; tmg[iy*35+ix] = tv;
    }
  }
  __syncthreads();

  const int ty = tid >> 5, tx = tid & 31;
  const int r0 = ty << 2;

  int c1[10], c2[10], c3[10];
  #pragma unroll
  for (int j = 0; j < 10; j++){
    unsigned w = (unsigned)(mrow[r0 + j] >> tx);
    c3[j] = __popc(w & 0x7Fu);
    c2[j] = __popc((w >> 1) & 0x1Fu);
    c1[j] = __popc((w >> 2) & 0x7u);
  }

  float P[3][3], Q[3][3], A[3][3], B[3][3];
  #pragma unroll
  for (int rr = 0; rr < 3; rr++)
    #pragma unroll
    for (int cc = 0; cc < 3; cc++){
      P[rr][cc] = sp[(r0+1+rr)*44 + tx+3+cc];
      Q[rr][cc] = st[(r0+1+rr)*44 + tx+3+cc];
      A[rr][cc] = pmg[(r0+rr)*35 + tx+cc];
      B[rr][cc] = tmg[(r0+rr)*35 + tx+cc];
    }

  float accg = 0.f, accs = 0.f, accl = 0.f;
  #pragma unroll
  for (int k = 0; k < 4; k++){
    if (k){
      #pragma unroll
      for (int cc = 0; cc < 3; cc++){
        P[0][cc]=P[1][cc]; P[1][cc]=P[2][cc]; P[2][cc]=sp[(r0+k+3)*44 + tx+3+cc];
        Q[0][cc]=Q[1][cc]; Q[1][cc]=Q[2][cc]; Q[2][cc]=st[(r0+k+3)*44 + tx+3+cc];
        A[0][cc]=A[1][cc]; A[1][cc]=A[2][cc]; A[2][cc]=pmg[(r0+k+2)*35 + tx+cc];
        B[0][cc]=B[1][cc]; B[1][cc]=B[2][cc]; B[2][cc]=tmg[(r0+k+2)*35 + tx+cc];
      }
    }
    float gxp = (P[0][2]+2.f*P[1][2]+P[2][2]) - (P[0][0]+2.f*P[1][0]+P[2][0]);
    float gyp = (P[2][0]+2.f*P[2][1]+P[2][2]) - (P[0][0]+2.f*P[0][1]+P[0][2]);
    float cvp = 4.f*P[1][1] - P[0][1] - P[1][0] - P[1][2] - P[2][1];
    float gxt = (Q[0][2]+2.f*Q[1][2]+Q[2][2]) - (Q[0][0]+2.f*Q[1][0]+Q[2][0]);
    float gyt = (Q[2][0]+2.f*Q[2][1]+Q[2][2]) - (Q[0][0]+2.f*Q[0][1]+Q[0][2]);
    float cvt = 4.f*Q[1][1] - Q[0][1] - Q[1][0] - Q[1][2] - Q[2][1];

    float sd = fabsf(A[1][1] - B[1][1]);
    float x1 = gxp + 1e-8f, y1 = gyp;
    float x2 = gxt + 1e-8f, y2 = gyt;
    float dd = fast_atan2_abs(fabsf(y1*x2 - x1*y2), x1*x2 + y1*y2);
    float cd = fabsf(cvp - cvt);

    int s1 = c1[k+2]+c1[k+3]+c1[k+4];
    int s2 = c2[k+1]+c2[k+2]+c2[k+3]+c2[k+4]+c2[k+5];
    int s3 = c3[k]+c3[k+1]+c3[k+2]+c3[k+3]+c3[k+4]+c3[k+5]+c3[k+6];
    float w1 = ((unsigned)(s1 - 1) <  8u) ? 1.f : 0.f;
    float w2 = ((unsigned)(s2 - 1) < 24u) ? 1.f : 0.f;
    float w3 = ((unsigned)(s3 - 1) < 48u) ? 1.f : 0.f;

    accg += (sd + dd) * (w1 + 0.5f*(w2 + w3)) + cd * (2.f*w1 + w2 + w3);

    float s9 = 0.f, s9q = 0.f;
    #pragma unroll
    for (int rr = 0; rr < 3; rr++)
      #pragma unroll
      for (int cc = 0; cc < 3; cc++){ s9 += P[rr][cc]; s9q += P[rr][cc]*P[rr][cc]; }
    float lm = s9 * (1.f/9.f), lq = s9q * (1.f/9.f);
    accs += fsqrt(fmaxf(lq - lm*lm, 1e-8f)) * w1;

    float psx = (A[0][2]+2.f*A[1][2]+A[2][2]) - (A[0][0]+2.f*A[1][0]+A[2][0]);
    float psy = (A[2][0]+2.f*A[2][1]+A[2][2]) - (A[0][0]+2.f*A[0][1]+A[0][2]);
    float pch = fsqrt(psx*psx + psy*psy + 1e-8f);
    float tsx = (B[0][2]+2.f*B[1][2]+B[2][2]) - (B[0][0]+2.f*B[1][0]+B[2][0]);
    float tsy = (B[2][0]+2.f*B[2][1]+B[2][2]) - (B[0][0]+2.f*B[0][1]+B[0][2]);
    float tch = fsqrt(tsx*tsx + tsy*tsy + 1e-8f);
    accl += fabsf(pch - tch) * w1;
  }

  float g  = block_reduce_add_f(accg, sc);
  float sm = block_reduce_add_f(accs, sc);
  float sl = block_reduce_add_f(accl, sc);
  if (tid == 0){
    int slot = (blockIdx.x + blockIdx.y * 7 + z * 13) & (NSLOT - 1);
    atomicAdd(&acc[0*NSLOT + slot], (double)g);
    atomicAdd(&acc[1*NSLOT + slot], (double)sm);
    atomicAdd(&acc[2*NSLOT + slot], (double)sl);
  }
}

// ---------------------------------------------------------------------------
// Lane-xor exchange (HW-verified R13): DPP for h=1,2,8; ds_swizzle h=4,16;
// bpermute h=32.
// ---------------------------------------------------------------------------
__device__ __forceinline__ float lane_xor(float x, int h, int lane){
  int xi = __float_as_int(x);
  int r;
  if (h == 1)       r = __builtin_amdgcn_update_dpp(xi, xi, 0xB1, 0xF, 0xF, true);
  else if (h == 2)  r = __builtin_amdgcn_update_dpp(xi, xi, 0x4E, 0xF, 0xF, true);
  else if (h == 8)  r = __builtin_amdgcn_update_dpp(xi, xi, 0x128, 0xF, 0xF, true);
  else if (h == 4)  r = __builtin_amdgcn_ds_swizzle(xi, 0x101F);  // xor4
  else if (h == 16) r = __builtin_amdgcn_ds_swizzle(xi, 0x401F);  // xor16
  else              r = __builtin_amdgcn_ds_bpermute((lane ^ 32) << 2, xi);
  return __int_as_float(r);
}

// ---------------------------------------------------------------------------
// Wave-level 1024-pt FFT: 64 (cross-lane) x 16 (in-register).
// Twiddle-before-exchange butterfly (R14): t = w_eff * v, exchange t,
// result = fma(sgn, t, partner_t). 8 VALU/butterfly. Log-depth power ladder.
// ---------------------------------------------------------------------------
#define FC 0.70710678118654752f
#define FC1 0.92387953251128676f
#define FS1 0.38268343236508977f

__device__ __forceinline__ void bfly(float2& a, float2& b){
  float tx = b.x, ty = b.y;
  b.x = a.x - tx; b.y = a.y - ty;
  a.x += tx;      a.y += ty;
}
__device__ __forceinline__ void cmul_c(float2& b, float wr, float wi){
  float tx = wr*b.x - wi*b.y, ty = wr*b.y + wi*b.x;
  b.x = tx; b.y = ty;
}
__device__ __forceinline__ void rotmi(float2& b){   // b *= -i
  float t = b.x; b.x = b.y; b.y = -t;
}

__device__ __forceinline__ void fft16_reg(float2* v){
  float2 y[16];
  y[0]=v[0];  y[1]=v[8];  y[2]=v[4];  y[3]=v[12];
  y[4]=v[2];  y[5]=v[10]; y[6]=v[6];  y[7]=v[14];
  y[8]=v[1];  y[9]=v[9];  y[10]=v[5]; y[11]=v[13];
  y[12]=v[3]; y[13]=v[11];y[14]=v[7]; y[15]=v[15];
  #pragma unroll
  for (int g = 0; g < 8; g++) bfly(y[2*g], y[2*g+1]);
  #pragma unroll
  for (int g = 0; g < 4; g++){
    int b = 4*g;
    bfly(y[b], y[b+2]);
    rotmi(y[b+3]); bfly(y[b+1], y[b+3]);
  }
  #pragma unroll
  for (int g = 0; g < 2; g++){
    int b = 8*g;
    bfly(y[b], y[b+4]);
    cmul_c(y[b+5],  FC, -FC); bfly(y[b+1], y[b+5]);
    rotmi(y[b+6]);            bfly(y[b+2], y[b+6]);
    cmul_c(y[b+7], -FC, -FC); bfly(y[b+3], y[b+7]);
  }
  bfly(y[0], y[8]);
  cmul_c(y[9],   FC1, -FS1); bfly(y[1], y[9]);
  cmul_c(y[10],  FC,  -FC);  bfly(y[2], y[10]);
  cmul_c(y[11],  FS1, -FC1); bfly(y[3], y[11]);
  rotmi(y[12]);              bfly(y[4], y[12]);
  cmul_c(y[13], -FS1, -FC1); bfly(y[5], y[13]);
  cmul_c(y[14], -FC,  -FC);  bfly(y[6], y[14]);
  cmul_c(y[15], -FC1, -FS1); bfly(y[7], y[15]);
  #pragma unroll
  for (int j = 0; j < 16; j++) v[j] = y[j];
}

__device__ __forceinline__ void fft1024_wave(float2* v, int lane,
                                             const float2* __restrict__ twg){
  // stage 0 (w = 1 for all lanes): t = v; exchange; v = partner_t + sgn*t
  {
    const float sgn = (lane & 1) ? -1.f : 1.f;
    #pragma unroll
    for (int j = 0; j < 16; j++){
      float ox = lane_xor(v[j].x, 1, lane);
      float oy = lane_xor(v[j].y, 1, lane);
      v[j].x = fmaf(sgn, v[j].x, ox);
      v[j].y = fmaf(sgn, v[j].y, oy);
    }
  }
  #pragma unroll
  for (int s = 1; s < 6; s++){
    const int h = 1 << s;
    const bool up = (lane & h) != 0;
    const float2 w = twg[(lane & (h - 1)) << (9 - s)];
    const float ewx = up ? w.x : 1.f;
    const float ewy = up ? w.y : 0.f;
    const float sgn = up ? -1.f : 1.f;
    #pragma unroll
    for (int j = 0; j < 16; j++){
      float tx = ewx*v[j].x - ewy*v[j].y;
      float ty = ewx*v[j].y + ewy*v[j].x;
      float ox = lane_xor(tx, h, lane);
      float oy = lane_xor(ty, h, lane);
      v[j].x = fmaf(sgn, tx, ox);
      v[j].y = fmaf(sgn, ty, oy);
    }
  }
  // per-slot twiddle: v[j] *= w^j, w = twg[lane]; log-depth powers
  float2 w1 = twg[lane];
  float2 w2 = cmulf(w1, w1);
  float2 w3 = cmulf(w2, w1);
  float2 w4 = cmulf(w2, w2);
  float2 w5 = cmulf(w3, w2);
  float2 w6 = cmulf(w3, w3);
  float2 w7 = cmulf(w4, w3);
  float2 w8 = cmulf(w4, w4);
  v[1]  = cmulf(v[1],  w1);
  v[2]  = cmulf(v[2],  w2);
  v[3]  = cmulf(v[3],  w3);
  v[4]  = cmulf(v[4],  w4);
  v[5]  = cmulf(v[5],  w5);
  v[6]  = cmulf(v[6],  w6);
  v[7]  = cmulf(v[7],  w7);
  v[8]  = cmulf(v[8],  w8);
  v[9]  = cmulf(cmulf(v[9],  w8), w1);
  v[10] = cmulf(cmulf(v[10], w8), w2);
  v[11] = cmulf(cmulf(v[11], w8), w3);
  v[12] = cmulf(cmulf(v[12], w8), w4);
  v[13] = cmulf(cmulf(v[13], w8), w5);
  v[14] = cmulf(cmulf(v[14], w8), w6);
  v[15] = cmulf(cmulf(v[15], w8), w7);
  fft16_reg(v);
}

// ---------------------------------------------------------------------------
// FFT pass 1 + tiled transpose: Zt layout [y>>3][k][y&7] (fp32 float2).
// 2-phase transpose (tile[8]) -> 4 barriers.
// ---------------------------------------------------------------------------
__global__ __launch_bounds__(512)
void fft_rows_t_kernel(const float* __restrict__ pred, const float* __restrict__ targ,
                       float2* __restrict__ Zt, const float2* __restrict__ twg){
  __shared__ float2 tile[8][64][9];
  const int tid = threadIdx.x;
  const int lane = tid & 63;
  const int w = tid >> 6;
  const int y0 = blockIdx.x << 3;
  const size_t ibase = ((size_t)blockIdx.y * HW + (y0 + w)) * HW;
  const int rb = __brev(lane) >> 26;
  const float4* p4 = (const float4*)(pred + ibase);
  const float4* t4 = (const float4*)(targ + ibase);
  float2 v[16];
  #pragma unroll
  for (int m = 0; m < 4; m++){
    float4 a = p4[4*rb + m];
    float4 b = t4[4*rb + m];
    v[4*m+0] = make_float2(a.x, b.x);
    v[4*m+1] = make_float2(a.y, b.y);
    v[4*m+2] = make_float2(a.z, b.z);
    v[4*m+3] = make_float2(a.w, b.w);
  }
  fft1024_wave(v, lane, twg);
  float2* zb = Zt + (size_t)blockIdx.y * HW * HW + (size_t)blockIdx.x * 8192;
  const int yl = tid & 7, kl = tid >> 3;
  #pragma unroll
  for (int jb = 0; jb < 2; jb++){
    __syncthreads();
    #pragma unroll
    for (int jj = 0; jj < 8; jj++) tile[jj][lane][w] = v[8*jb + jj];
    __syncthreads();
    #pragma unroll
    for (int jj = 0; jj < 8; jj++){
      int k = ((jb << 3) + jj) * 64 + kl;
      zb[k * 8 + yl] = tile[jj][kl][yl];     // contiguous across the block
    }
  }
}

// ---------------------------------------------------------------------------
// FFT pass 2 + reduce: one FFT per wave, Hermitian partner via natural-order
// LDS. Reads the tiled Zt: lane's 16-y chunk = two 64-B contiguous segments.
// ---------------------------------------------------------------------------
__device__ __forceinline__ void freq_contrib(float2 Zk, float2 Zm, int k1, int k2,
                                             float& ms, float& ps){
  int di = k1 - 512, dj = k2 - 512;
  if (di*di + dj*dj < 94372) return;         // dist > 307.2  <=>  r2 >= 94372
  float pr = 0.5f*(Zk.x + Zm.x);
  float pi = 0.5f*(Zk.y - Zm.y);
  float tr = 0.5f*(Zk.y + Zm.y);
  float ti = 0.5f*(Zm.x - Zk.x);
  float p2 = pr*pr + pi*pi;
  float t2 = tr*tr + ti*ti;
  ms += p2 + t2 - 2.f*fsqrt(p2*t2);
  float re = pr*tr + pi*ti;
  float im = pi*tr - pr*ti;
  float pd = fast_atan2_abs(fabsf(im), re);  // squared below; sign irrelevant
  ps += pd*pd;
}

__global__ __launch_bounds__(256)
void fft_cols2_kernel(const float2* __restrict__ Z, const float2* __restrict__ twg,
                      double* __restrict__ acc){
  __shared__ float2 ex[4][1024];            // per-wave natural-order spectrum
  const int lane = threadIdx.x & 63;
  const int w = threadIdx.x >> 6;           // 0..3
  const int p = 2 * blockIdx.x + (w >> 1);  // pair index, 0..512 valid
  const bool valid = (p <= 512);
  const int r = (w & 1) ? ((1024 - p) & 1023) : p;   // this wave's Zt row (k)
  const float2* base = Z + (size_t)blockIdx.y * HW * HW;
  const int rb = __brev(lane) >> 26;

  float2 v[16];
  if (valid){
    const float4* f4 = (const float4*)base;
    #pragma unroll
    for (int s = 0; s < 2; s++){
      size_t o = (size_t)(2*rb + s) * 4096 + (size_t)r * 4;  // float4 units
      #pragma unroll
      for (int q = 0; q < 4; q++){
        float4 x = f4[o + q];
        v[8*s + 2*q]     = make_float2(x.x, x.y);
        v[8*s + 2*q + 1] = make_float2(x.z, x.w);
      }
    }
    fft1024_wave(v, lane, twg);
    #pragma unroll
    for (int j = 0; j < 16; j++) ex[w][lane + (j << 6)] = v[j];
  }
  __syncthreads();
  if (!valid) return;
  const bool self = (p == 0) || (p == 512);
  if ((w & 1) && self) return;              // duplicate row: LDS written, no contribs

  const float2* pb = ex[w ^ 1];             // partner spectrum, natural order
  float ms = 0.f, ps = 0.f;
  #pragma unroll
  for (int j = 0; j < 16; j++){
    int k = lane + (j << 6);
    float2 zm = pb[(1024 - k) & 1023];      // Z_partner(-k)
    freq_contrib(v[j], zm, k, r, ms, ps);
  }
  #pragma unroll
  for (int o = 32; o > 0; o >>= 1){
    ms += __shfl_down(ms, o, 64);
    ps += __shfl_down(ps, o, 64);
  }
  if (lane == 0){
    int slot = (r + blockIdx.y * 11) & (NSLOT - 1);
    atomicAdd(&acc[3*NSLOT + slot], (double)ms);
    atomicAdd(&acc[4*NSLOT + slot], (double)ps);
  }
}

// ---------------------------------------------------------------------------
__global__ void finalize_kernel(const double* __restrict__ acc, float* __restrict__ out){
  const int t = threadIdx.x;   // 64 threads
  double v[5];
  #pragma unroll
  for (int s = 0; s < 5; s++) v[s] = acc[s*NSLOT + t];
  #pragma unroll
  for (int o = 32; o > 0; o >>= 1)
    #pragma unroll
    for (int s = 0; s < 5; s++) v[s] += __shfl_down(v[s], o, 64);
  if (t == 0){
    const double inv = 1.0 / 8388608.0;      // mean over 8*1024*1024
    double grad   = v[0] * inv / 3.0;        // / len(bms)
    double smooth = v[1] * inv;
    double slope  = v[2] * inv;
    double freq   = (v[3] + 2.0 * v[4]) * inv;
    double total  = 2.0*grad + 1.5*freq + 3.0*smooth + 2.0*slope;
    out[0] = (float)total;
    out[1] = (float)grad;
    out[2] = (float)freq;
    out[3] = (float)smooth;
    out[4] = (float)slope;
  }
}

extern "C" void kernel_launch(void* const* d_in, const int* in_sizes, int n_in,
                              void* d_out, int out_size, void* d_ws, size_t ws_size,
                              hipStream_t stream){
  const float* pred = (const float*)d_in[0];
  const float* targ = (const float*)d_in[1];
  const float* mask = (const float*)d_in[2];
  double* acc  = (double*)d_ws;                         // [0, 2560)
  float2* twg  = (float2*)((char*)d_ws + 4096);         // [4096, 8192)
  float2* Z    = (float2*)((char*)d_ws + 8192);         // 8 x 8 MiB fp32 images
  // ws_size ~256 MiB (measured R9) — 64 MiB Z fits with margin.

  setup_kernel<<<2, 256, 0, stream>>>(acc, twg);
  spatial_kernel<<<dim3(32, 32, 8), 256, 0, stream>>>(pred, targ, mask, acc);
  fft_rows_t_kernel<<<dim3(128, 8), 512, 0, stream>>>(pred, targ, Z, twg);
  fft_cols2_kernel<<<dim3(257, 8), 256, 0, stream>>>(Z, twg, acc);
  finalize_kernel<<<1, 64, 0, stream>>>(acc, (float*)d_out);
}

// Round 3
// 227.377 us; speedup vs baseline: 1.1691x; 1.0350x over previous
//
#include <hip/hip_runtime.h>

#define HW 1024
#define TWO_PI_F 6.28318530717958647692f
#define NSLOT 64   // atomic spreading: 64 slots per accumulator, 5 accumulators

typedef float v2f __attribute__((ext_vector_type(2)));
typedef int   i2v __attribute__((ext_vector_type(2)));

__device__ __forceinline__ v2f mkv2(float a, float b){ v2f r; r.x = a; r.y = b; return r; }
__device__ __forceinline__ v2f v2s(float s){ v2f r; r.x = s; r.y = s; return r; }

__device__ __forceinline__ float2 cmulf(float2 a, float2 b){
  return make_float2(a.x*b.x - a.y*b.y, a.x*b.y + a.y*b.x);
}
__device__ __forceinline__ float fsqrt(float x){ return __builtin_amdgcn_sqrtf(x); }

// fast |atan2|: caller passes ay = |y| >= 0. Saves the final sign-select.
__device__ __forceinline__ float fast_atan2_abs(float ay, float x){
  float ax = fabsf(x);
  float mx = fmaxf(ax, ay), mn = fminf(ax, ay);
  float a  = mn * __builtin_amdgcn_rcpf(fmaxf(mx, 1e-37f));
  float s  = a * a;
  float r  = ((((0.0208351f*s - 0.085133f)*s + 0.180141f)*s - 0.3302995f)*s
              + 0.999866f) * a;
  r = (ay > ax) ? 1.57079632679f - r : r;
  return (x < 0.f) ? 3.14159265359f - r : r;
}

// 256-thread block reduction (4 waves of 64), float
__device__ __forceinline__ float block_reduce_add_f(float v, float* sc){
  int tid = threadIdx.x;
  #pragma unroll
  for (int o = 32; o > 0; o >>= 1) v += __shfl_down(v, o, 64);
  __syncthreads();
  if ((tid & 63) == 0) sc[tid >> 6] = v;
  __syncthreads();
  return sc[0] + sc[1] + sc[2] + sc[3];
}

// merged setup: zero accumulators + twiddle table (one launch)
__global__ void setup_kernel(double* acc, float2* twg){
  int i = threadIdx.x + blockIdx.x * 256;   // grid 2 x 256 -> 0..511
  if (i < 5 * NSLOT) acc[i] = 0.0;
  if (i < 512){
    float s, c; sincosf(-TWO_PI_F * (float)i * (1.f/1024.f), &s, &c);
    twg[i] = make_float2(c, s);
  }
}

// ---------------------------------------------------------------------------
// Spatial half: 32x32 tile/block, 4 px/thread, one dispatch.
// R16: (pred,targ) packed as v2f -> v_pk_* double-rate f32 for all symmetric
// arithmetic (sobel, laplacian, mag, slope-sobel) and ds_read_b64 paired LDS
// access (halves LDS op count). Popcounts packed 3-per-int (fields can't
// carry: sums <= 21/35/49 < 256). LDS total unchanged ~22.5 KB.
// ---------------------------------------------------------------------------
__global__ __launch_bounds__(256, 4)
void spatial_kernel(const float* __restrict__ pred, const float* __restrict__ targ,
                    const float* __restrict__ mask, double* __restrict__ acc){
  __shared__ v2f spt[36*44];               // (pred, targ) halo tile, stride 44
  __shared__ v2f pmt[34*35];               // union: smkf float[38*41] / (pmag,tmag)
  __shared__ unsigned long long mrow[38];
  __shared__ float sc[4];
  float* const smkf = (float*)pmt;         // 1558 floats = 6232 B <= 9520 B

  const int tid = threadIdx.x;
  const int x0 = blockIdx.x << 5, y0 = blockIdx.y << 5;
  const int z = blockIdx.z;
  const size_t ib = (size_t)z * ((size_t)HW * HW);
  const bool interior = ((unsigned)(blockIdx.x - 1) < 30u) &&
                        ((unsigned)(blockIdx.y - 1) < 30u);

  if (interior){
    const float* pb = pred + ib;
    const float* tb = targ + ib;
    for (int i = tid; i < 360; i += 256){        // 36 rows x 10 float4 (40 cols)
      int a = i / 10, b = i % 10;
      size_t off = (size_t)(y0 - 2 + a) * HW + (x0 - 4 + 4*b);
      float4 pv = *(const float4*)(pb + off);
      float4 tv = *(const float4*)(tb + off);
      int o = a*44 + 4*b;
      spt[o+0] = mkv2(pv.x, tv.x);
      spt[o+1] = mkv2(pv.y, tv.y);
      spt[o+2] = mkv2(pv.z, tv.z);
      spt[o+3] = mkv2(pv.w, tv.w);
    }
    const float* mb = mask + ib;
    for (int i = tid; i < 380; i += 256){        // 38 rows x 10 float4
      int a = i / 10, b = i % 10;
      size_t off = (size_t)(y0 - 3 + a) * HW + (x0 - 4 + 4*b);
      float4 v = *(const float4*)(mb + off);
      int o = a*41 + 4*b;
      smkf[o]=v.x; smkf[o+1]=v.y; smkf[o+2]=v.z; smkf[o+3]=v.w;
    }
  } else {
    for (int i = tid; i < 1296; i += 256){
      int a = i / 36, b = i % 36;
      int gy = y0 - 2 + a, gx = x0 - 2 + b;
      float pv = 0.f, tv = 0.f;
      if ((unsigned)gy < HW && (unsigned)gx < HW){
        size_t idx = ib + (size_t)gy * HW + gx;
        pv = pred[idx]; tv = targ[idx];
      }
      spt[a*44 + b + 2] = mkv2(pv, tv);
    }
    for (int i = tid; i < 1444; i += 256){
      int a = i / 38, b = i % 38;
      int gy = y0 - 3 + a, gx = x0 - 3 + b;
      float v = 0.f;
      if ((unsigned)gy < HW && (unsigned)gx < HW) v = mask[ib + (size_t)gy * HW + gx];
      smkf[a*41 + b + 1] = v;
    }
  }
  __syncthreads();

  unsigned long long mw = 0ull;
  if (tid < 38){
    #pragma unroll
    for (int x = 0; x < 38; x++)
      mw |= (smkf[tid*41 + 1 + x] > 0.5f) ? (1ull << x) : 0ull;
  }
  __syncthreads();                              // smkf reads done; pmt reuse ok
  if (tid < 38) mrow[tid] = mw;

  if (interior){
    for (int i = tid; i < 1156; i += 256){      // no bounds checks: always in-range
      int iy = i / 34, ix = i % 34;
      int o = iy*44 + ix + 2;
      v2f a00=spt[o],    a01=spt[o+1],  a02=spt[o+2];
      v2f a10=spt[o+44],                a12=spt[o+46];
      v2f a20=spt[o+88], a21=spt[o+89], a22=spt[o+90];
      v2f gx = (a02 + v2s(2.f)*a12 + a22) - (a00 + v2s(2.f)*a10 + a20);
      v2f gy = (a20 + v2s(2.f)*a21 + a22) - (a00 + v2s(2.f)*a01 + a02);
      v2f m2 = gx*gx + gy*gy + v2s(1e-8f);
      pmt[iy*35+ix] = mkv2(fsqrt(m2.x), fsqrt(m2.y));
    }
  } else {
    for (int i = tid; i < 1156; i += 256){
      int iy = i / 34, ix = i % 34;
      int gy = y0 - 1 + iy, gx = x0 - 1 + ix;
      v2f out = v2s(0.f);
      if ((unsigned)gy < HW && (unsigned)gx < HW){
        int o = iy*44 + ix + 2;
        v2f a00=spt[o],    a01=spt[o+1],  a02=spt[o+2];
        v2f a10=spt[o+44],                a12=spt[o+46];
        v2f a20=spt[o+88], a21=spt[o+89], a22=spt[o+90];
        v2f gxv = (a02 + v2s(2.f)*a12 + a22) - (a00 + v2s(2.f)*a10 + a20);
        v2f gyv = (a20 + v2s(2.f)*a21 + a22) - (a00 + v2s(2.f)*a01 + a02);
        v2f m2 = gxv*gxv + gyv*gyv + v2s(1e-8f);
        out = mkv2(fsqrt(m2.x), fsqrt(m2.y));
      }
      pmt[iy*35+ix] = out;
    }
  }
  __syncthreads();

  const int ty = tid >> 5, tx = tid & 31;
  const int r0 = ty << 2;

  // packed counts: cp[j] = c1 | c2<<8 | c3<<16 (vertical sums can't carry)
  int cp[10];
  #pragma unroll
  for (int j = 0; j < 10; j++){
    unsigned w = (unsigned)(mrow[r0 + j] >> tx);
    int c3 = __popc(w & 0x7Fu);
    int c2 = __popc((w >> 1) & 0x1Fu);
    int c1 = __popc((w >> 2) & 0x7u);
    cp[j] = c1 | (c2 << 8) | (c3 << 16);
  }

  v2f PQ[3][3], AB[3][3];
  #pragma unroll
  for (int rr = 0; rr < 3; rr++)
    #pragma unroll
    for (int cc = 0; cc < 3; cc++){
      PQ[rr][cc] = spt[(r0+1+rr)*44 + tx+3+cc];
      AB[rr][cc] = pmt[(r0+rr)*35 + tx+cc];
    }

  float accg = 0.f, accs = 0.f, accl = 0.f;
  #pragma unroll
  for (int k = 0; k < 4; k++){
    if (k){
      #pragma unroll
      for (int cc = 0; cc < 3; cc++){
        PQ[0][cc]=PQ[1][cc]; PQ[1][cc]=PQ[2][cc]; PQ[2][cc]=spt[(r0+k+3)*44 + tx+3+cc];
        AB[0][cc]=AB[1][cc]; AB[1][cc]=AB[2][cc]; AB[2][cc]=pmt[(r0+k+2)*35 + tx+cc];
      }
    }
    v2f gxv = (PQ[0][2] + v2s(2.f)*PQ[1][2] + PQ[2][2]) - (PQ[0][0] + v2s(2.f)*PQ[1][0] + PQ[2][0]);
    v2f gyv = (PQ[2][0] + v2s(2.f)*PQ[2][1] + PQ[2][2]) - (PQ[0][0] + v2s(2.f)*PQ[0][1] + PQ[0][2]);
    v2f cvv = v2s(4.f)*PQ[1][1] - PQ[0][1] - PQ[1][0] - PQ[1][2] - PQ[2][1];

    float sd = fabsf(AB[1][1].x - AB[1][1].y);
    float x1 = gxv.x + 1e-8f, y1 = gyv.x;
    float x2 = gxv.y + 1e-8f, y2 = gyv.y;
    float dd = fast_atan2_abs(fabsf(y1*x2 - x1*y2), x1*x2 + y1*y2);
    float cd = fabsf(cvv.x - cvv.y);

    int s1p = cp[k+2] + cp[k+3] + cp[k+4];
    int s2p = s1p + cp[k+1] + cp[k+5];
    int s3p = s2p + cp[k]   + cp[k+6];
    int s1 = s1p & 0xFF;
    int s2 = (s2p >> 8) & 0xFF;
    int s3 = s3p >> 16;
    float w1 = ((unsigned)(s1 - 1) <  8u) ? 1.f : 0.f;
    float w2 = ((unsigned)(s2 - 1) < 24u) ? 1.f : 0.f;
    float w3 = ((unsigned)(s3 - 1) < 48u) ? 1.f : 0.f;

    accg += (sd + dd) * (w1 + 0.5f*(w2 + w3)) + cd * (2.f*w1 + w2 + w3);

    float s9 = 0.f, s9q = 0.f;
    #pragma unroll
    for (int rr = 0; rr < 3; rr++)
      #pragma unroll
      for (int cc = 0; cc < 3; cc++){ float p = PQ[rr][cc].x; s9 += p; s9q += p*p; }
    float lm = s9 * (1.f/9.f), lq = s9q * (1.f/9.f);
    accs += fsqrt(fmaxf(lq - lm*lm, 1e-8f)) * w1;

    v2f px = (AB[0][2] + v2s(2.f)*AB[1][2] + AB[2][2]) - (AB[0][0] + v2s(2.f)*AB[1][0] + AB[2][0]);
    v2f py = (AB[2][0] + v2s(2.f)*AB[2][1] + AB[2][2]) - (AB[0][0] + v2s(2.f)*AB[0][1] + AB[0][2]);
    v2f ch2 = px*px + py*py + v2s(1e-8f);
    accl += fabsf(fsqrt(ch2.x) - fsqrt(ch2.y)) * w1;
  }

  float g  = block_reduce_add_f(accg, sc);
  float sm = block_reduce_add_f(accs, sc);
  float sl = block_reduce_add_f(accl, sc);
  if (tid == 0){
    int slot = (blockIdx.x + blockIdx.y * 7 + z * 13) & (NSLOT - 1);
    atomicAdd(&acc[0*NSLOT + slot], (double)g);
    atomicAdd(&acc[1*NSLOT + slot], (double)sm);
    atomicAdd(&acc[2*NSLOT + slot], (double)sl);
  }
}

// ---------------------------------------------------------------------------
// Lane-xor exchange: DPP for h=1,2,8 (0x128 = ROW_ROR:8 == xor8 within row);
// ds_swizzle h=4,16 (no DPP encoding for xor4/xor16);
// R16: h=32 via v_permlane32_swap_b32 (VALU, 1.2x vs ds_bpermute per m255).
// ---------------------------------------------------------------------------
__device__ __forceinline__ float lane_xor(float x, int h, int lane){
  int xi = __float_as_int(x);
  int r;
  if (h == 1)       r = __builtin_amdgcn_update_dpp(xi, xi, 0xB1, 0xF, 0xF, true);
  else if (h == 2)  r = __builtin_amdgcn_update_dpp(xi, xi, 0x4E, 0xF, 0xF, true);
  else if (h == 8)  r = __builtin_amdgcn_update_dpp(xi, xi, 0x128, 0xF, 0xF, true);
  else if (h == 4)  r = __builtin_amdgcn_ds_swizzle(xi, 0x101F);  // xor4
  else if (h == 16) r = __builtin_amdgcn_ds_swizzle(xi, 0x401F);  // xor16
  else {
    i2v pr = __builtin_amdgcn_permlane32_swap(xi, xi, false, false);
    r = (lane & 32) ? pr.x : pr.y;   // x: lanes>=32 got partner; y: lanes<32
  }
  return __int_as_float(r);
}

// ---------------------------------------------------------------------------
// Wave-level 1024-pt FFT: 64 (cross-lane) x 16 (in-register).
// Twiddle-before-exchange butterfly: t = w_eff * v, exchange t,
// result = fma(sgn, t, partner_t). 8 VALU/butterfly. Log-depth power ladder.
// ---------------------------------------------------------------------------
#define FC 0.70710678118654752f
#define FC1 0.92387953251128676f
#define FS1 0.38268343236508977f

__device__ __forceinline__ void bfly(float2& a, float2& b){
  float tx = b.x, ty = b.y;
  b.x = a.x - tx; b.y = a.y - ty;
  a.x += tx;      a.y += ty;
}
__device__ __forceinline__ void cmul_c(float2& b, float wr, float wi){
  float tx = wr*b.x - wi*b.y, ty = wr*b.y + wi*b.x;
  b.x = tx; b.y = ty;
}
__device__ __forceinline__ void rotmi(float2& b){   // b *= -i
  float t = b.x; b.x = b.y; b.y = -t;
}

__device__ __forceinline__ void fft16_reg(float2* v){
  float2 y[16];
  y[0]=v[0];  y[1]=v[8];  y[2]=v[4];  y[3]=v[12];
  y[4]=v[2];  y[5]=v[10]; y[6]=v[6];  y[7]=v[14];
  y[8]=v[1];  y[9]=v[9];  y[10]=v[5]; y[11]=v[13];
  y[12]=v[3]; y[13]=v[11];y[14]=v[7]; y[15]=v[15];
  #pragma unroll
  for (int g = 0; g < 8; g++) bfly(y[2*g], y[2*g+1]);
  #pragma unroll
  for (int g = 0; g < 4; g++){
    int b = 4*g;
    bfly(y[b], y[b+2]);
    rotmi(y[b+3]); bfly(y[b+1], y[b+3]);
  }
  #pragma unroll
  for (int g = 0; g < 2; g++){
    int b = 8*g;
    bfly(y[b], y[b+4]);
    cmul_c(y[b+5],  FC, -FC); bfly(y[b+1], y[b+5]);
    rotmi(y[b+6]);            bfly(y[b+2], y[b+6]);
    cmul_c(y[b+7], -FC, -FC); bfly(y[b+3], y[b+7]);
  }
  bfly(y[0], y[8]);
  cmul_c(y[9],   FC1, -FS1); bfly(y[1], y[9]);
  cmul_c(y[10],  FC,  -FC);  bfly(y[2], y[10]);
  cmul_c(y[11],  FS1, -FC1); bfly(y[3], y[11]);
  rotmi(y[12]);              bfly(y[4], y[12]);
  cmul_c(y[13], -FS1, -FC1); bfly(y[5], y[13]);
  cmul_c(y[14], -FC,  -FC);  bfly(y[6], y[14]);
  cmul_c(y[15], -FC1, -FS1); bfly(y[7], y[15]);
  #pragma unroll
  for (int j = 0; j < 16; j++) v[j] = y[j];
}

__device__ __forceinline__ void fft1024_wave(float2* v, int lane,
                                             const float2* __restrict__ twg){
  // stage 0 (w = 1 for all lanes): t = v; exchange; v = partner_t + sgn*t
  {
    const float sgn = (lane & 1) ? -1.f : 1.f;
    #pragma unroll
    for (int j = 0; j < 16; j++){
      float ox = lane_xor(v[j].x, 1, lane);
      float oy = lane_xor(v[j].y, 1, lane);
      v[j].x = fmaf(sgn, v[j].x, ox);
      v[j].y = fmaf(sgn, v[j].y, oy);
    }
  }
  #pragma unroll
  for (int s = 1; s < 6; s++){
    const int h = 1 << s;
    const bool up = (lane & h) != 0;
    const float2 w = twg[(lane & (h - 1)) << (9 - s)];
    const float ewx = up ? w.x : 1.f;
    const float ewy = up ? w.y : 0.f;
    const float sgn = up ? -1.f : 1.f;
    #pragma unroll
    for (int j = 0; j < 16; j++){
      float tx = ewx*v[j].x - ewy*v[j].y;
      float ty = ewx*v[j].y + ewy*v[j].x;
      float ox = lane_xor(tx, h, lane);
      float oy = lane_xor(ty, h, lane);
      v[j].x = fmaf(sgn, tx, ox);
      v[j].y = fmaf(sgn, ty, oy);
    }
  }
  // per-slot twiddle: v[j] *= w^j, w = twg[lane]; log-depth powers
  float2 w1 = twg[lane];
  float2 w2 = cmulf(w1, w1);
  float2 w3 = cmulf(w2, w1);
  float2 w4 = cmulf(w2, w2);
  float2 w5 = cmulf(w3, w2);
  float2 w6 = cmulf(w3, w3);
  float2 w7 = cmulf(w4, w3);
  float2 w8 = cmulf(w4, w4);
  v[1]  = cmulf(v[1],  w1);
  v[2]  = cmulf(v[2],  w2);
  v[3]  = cmulf(v[3],  w3);
  v[4]  = cmulf(v[4],  w4);
  v[5]  = cmulf(v[5],  w5);
  v[6]  = cmulf(v[6],  w6);
  v[7]  = cmulf(v[7],  w7);
  v[8]  = cmulf(v[8],  w8);
  v[9]  = cmulf(cmulf(v[9],  w8), w1);
  v[10] = cmulf(cmulf(v[10], w8), w2);
  v[11] = cmulf(cmulf(v[11], w8), w3);
  v[12] = cmulf(cmulf(v[12], w8), w4);
  v[13] = cmulf(cmulf(v[13], w8), w5);
  v[14] = cmulf(cmulf(v[14], w8), w6);
  v[15] = cmulf(cmulf(v[15], w8), w7);
  fft16_reg(v);
}

// ---------------------------------------------------------------------------
// FFT pass 1 + tiled transpose: Zt layout [y>>3][k][y&7] (fp32 float2).
// 2-phase transpose (tile[8]) -> 4 barriers.
// ---------------------------------------------------------------------------
__global__ __launch_bounds__(512)
void fft_rows_t_kernel(const float* __restrict__ pred, const float* __restrict__ targ,
                       float2* __restrict__ Zt, const float2* __restrict__ twg){
  __shared__ float2 tile[8][64][9];
  const int tid = threadIdx.x;
  const int lane = tid & 63;
  const int w = tid >> 6;
  const int y0 = blockIdx.x << 3;
  const size_t ibase = ((size_t)blockIdx.y * HW + (y0 + w)) * HW;
  const int rb = __brev(lane) >> 26;
  const float4* p4 = (const float4*)(pred + ibase);
  const float4* t4 = (const float4*)(targ + ibase);
  float2 v[16];
  #pragma unroll
  for (int m = 0; m < 4; m++){
    float4 a = p4[4*rb + m];
    float4 b = t4[4*rb + m];
    v[4*m+0] = make_float2(a.x, b.x);
    v[4*m+1] = make_float2(a.y, b.y);
    v[4*m+2] = make_float2(a.z, b.z);
    v[4*m+3] = make_float2(a.w, b.w);
  }
  fft1024_wave(v, lane, twg);
  float2* zb = Zt + (size_t)blockIdx.y * HW * HW + (size_t)blockIdx.x * 8192;
  const int yl = tid & 7, kl = tid >> 3;
  #pragma unroll
  for (int jb = 0; jb < 2; jb++){
    __syncthreads();
    #pragma unroll
    for (int jj = 0; jj < 8; jj++) tile[jj][lane][w] = v[8*jb + jj];
    __syncthreads();
    #pragma unroll
    for (int jj = 0; jj < 8; jj++){
      int k = ((jb << 3) + jj) * 64 + kl;
      zb[k * 8 + yl] = tile[jj][kl][yl];     // contiguous across the block
    }
  }
}

// ---------------------------------------------------------------------------
// FFT pass 2 + reduce: one FFT per wave, Hermitian partner via natural-order
// LDS. Reads the tiled Zt: lane's 16-y chunk = two 64-B contiguous segments.
// ---------------------------------------------------------------------------
__device__ __forceinline__ void freq_contrib(float2 Zk, float2 Zm, int k1, int k2,
                                             float& ms, float& ps){
  int di = k1 - 512, dj = k2 - 512;
  if (di*di + dj*dj < 94372) return;         // dist > 307.2  <=>  r2 >= 94372
  float pr = 0.5f*(Zk.x + Zm.x);
  float pi = 0.5f*(Zk.y - Zm.y);
  float tr = 0.5f*(Zk.y + Zm.y);
  float ti = 0.5f*(Zm.x - Zk.x);
  float p2 = pr*pr + pi*pi;
  float t2 = tr*tr + ti*ti;
  ms += p2 + t2 - 2.f*fsqrt(p2*t2);
  float re = pr*tr + pi*ti;
  float im = pi*tr - pr*ti;
  float pd = fast_atan2_abs(fabsf(im), re);  // squared below; sign irrelevant
  ps += pd*pd;
}

__global__ __launch_bounds__(256)
void fft_cols2_kernel(const float2* __restrict__ Z, const float2* __restrict__ twg,
                      double* __restrict__ acc){
  __shared__ float2 ex[4][1024];            // per-wave natural-order spectrum
  const int lane = threadIdx.x & 63;
  const int w = threadIdx.x >> 6;           // 0..3
  const int p = 2 * blockIdx.x + (w >> 1);  // pair index, 0..512 valid
  const bool valid = (p <= 512);
  const int r = (w & 1) ? ((1024 - p) & 1023) : p;   // this wave's Zt row (k)
  const float2* base = Z + (size_t)blockIdx.y * HW * HW;
  const int rb = __brev(lane) >> 26;

  float2 v[16];
  if (valid){
    const float4* f4 = (const float4*)base;
    #pragma unroll
    for (int s = 0; s < 2; s++){
      size_t o = (size_t)(2*rb + s) * 4096 + (size_t)r * 4;  // float4 units
      #pragma unroll
      for (int q = 0; q < 4; q++){
        float4 x = f4[o + q];
        v[8*s + 2*q]     = make_float2(x.x, x.y);
        v[8*s + 2*q + 1] = make_float2(x.z, x.w);
      }
    }
    fft1024_wave(v, lane, twg);
    #pragma unroll
    for (int j = 0; j < 16; j++) ex[w][lane + (j << 6)] = v[j];
  }
  __syncthreads();
  if (!valid) return;
  const bool self = (p == 0) || (p == 512);
  if ((w & 1) && self) return;              // duplicate row: LDS written, no contribs

  const float2* pb = ex[w ^ 1];             // partner spectrum, natural order
  float ms = 0.f, ps = 0.f;
  #pragma unroll
  for (int j = 0; j < 16; j++){
    int k = lane + (j << 6);
    float2 zm = pb[(1024 - k) & 1023];      // Z_partner(-k)
    freq_contrib(v[j], zm, k, r, ms, ps);
  }
  #pragma unroll
  for (int o = 32; o > 0; o >>= 1){
    ms += __shfl_down(ms, o, 64);
    ps += __shfl_down(ps, o, 64);
  }
  if (lane == 0){
    int slot = (r + blockIdx.y * 11) & (NSLOT - 1);
    atomicAdd(&acc[3*NSLOT + slot], (double)ms);
    atomicAdd(&acc[4*NSLOT + slot], (double)ps);
  }
}

// ---------------------------------------------------------------------------
__global__ void finalize_kernel(const double* __restrict__ acc, float* __restrict__ out){
  const int t = threadIdx.x;   // 64 threads
  double v[5];
  #pragma unroll
  for (int s = 0; s < 5; s++) v[s] = acc[s*NSLOT + t];
  #pragma unroll
  for (int o = 32; o > 0; o >>= 1)
    #pragma unroll
    for (int s = 0; s < 5; s++) v[s] += __shfl_down(v[s], o, 64);
  if (t == 0){
    const double inv = 1.0 / 8388608.0;      // mean over 8*1024*1024
    double grad   = v[0] * inv / 3.0;        // / len(bms)
    double smooth = v[1] * inv;
    double slope  = v[2] * inv;
    double freq   = (v[3] + 2.0 * v[4]) * inv;
    double total  = 2.0*grad + 1.5*freq + 3.0*smooth + 2.0*slope;
    out[0] = (float)total;
    out[1] = (float)grad;
    out[2] = (float)freq;
    out[3] = (float)smooth;
    out[4] = (float)slope;
  }
}

extern "C" void kernel_launch(void* const* d_in, const int* in_sizes, int n_in,
                              void* d_out, int out_size, void* d_ws, size_t ws_size,
                              hipStream_t stream){
  const float* pred = (const float*)d_in[0];
  const float* targ = (const float*)d_in[1];
  const float* mask = (const float*)d_in[2];
  double* acc  = (double*)d_ws;                         // [0, 2560)
  float2* twg  = (float2*)((char*)d_ws + 4096);         // [4096, 8192)
  float2* Z    = (float2*)((char*)d_ws + 8192);         // 8 x 8 MiB fp32 images
  // ws_size ~256 MiB (measured R9) — 64 MiB Z fits with margin.

  setup_kernel<<<2, 256, 0, stream>>>(acc, twg);
  spatial_kernel<<<dim3(32, 32, 8), 256, 0, stream>>>(pred, targ, mask, acc);
  fft_rows_t_kernel<<<dim3(128, 8), 512, 0, stream>>>(pred, targ, Z, twg);
  fft_cols2_kernel<<<dim3(257, 8), 256, 0, stream>>>(Z, twg, acc);
  finalize_kernel<<<1, 64, 0, stream>>>(acc, (float*)d_out);
}

// Round 4
// 225.764 us; speedup vs baseline: 1.1775x; 1.0071x over previous
//
#include <hip/hip_runtime.h>

#define HW 1024
#define TWO_PI_F 6.28318530717958647692f
#define NSLOT 64   // atomic spreading: 64 slots per accumulator, 5 accumulators

typedef float v2f __attribute__((ext_vector_type(2)));
typedef int   i2v __attribute__((ext_vector_type(2)));

__device__ __forceinline__ v2f mkv2(float a, float b){ v2f r; r.x = a; r.y = b; return r; }
__device__ __forceinline__ v2f v2s(float s){ v2f r; r.x = s; r.y = s; return r; }

__device__ __forceinline__ float2 cmulf(float2 a, float2 b){
  return make_float2(a.x*b.x - a.y*b.y, a.x*b.y + a.y*b.x);
}
__device__ __forceinline__ float fsqrt(float x){ return __builtin_amdgcn_sqrtf(x); }

// fast |atan2|: caller passes ay = |y| >= 0. Saves the final sign-select.
__device__ __forceinline__ float fast_atan2_abs(float ay, float x){
  float ax = fabsf(x);
  float mx = fmaxf(ax, ay), mn = fminf(ax, ay);
  float a  = mn * __builtin_amdgcn_rcpf(fmaxf(mx, 1e-37f));
  float s  = a * a;
  float r  = ((((0.0208351f*s - 0.085133f)*s + 0.180141f)*s - 0.3302995f)*s
              + 0.999866f) * a;
  r = (ay > ax) ? 1.57079632679f - r : r;
  return (x < 0.f) ? 3.14159265359f - r : r;
}

// 256-thread block reduction (4 waves of 64), float
__device__ __forceinline__ float block_reduce_add_f(float v, float* sc){
  int tid = threadIdx.x;
  #pragma unroll
  for (int o = 32; o > 0; o >>= 1) v += __shfl_down(v, o, 64);
  __syncthreads();
  if ((tid & 63) == 0) sc[tid >> 6] = v;
  __syncthreads();
  return sc[0] + sc[1] + sc[2] + sc[3];
}

// merged setup: zero accumulators + twiddle table (one launch)
__global__ void setup_kernel(double* acc, float2* twg){
  int i = threadIdx.x + blockIdx.x * 256;   // grid 2 x 256 -> 0..511
  if (i < 5 * NSLOT) acc[i] = 0.0;
  if (i < 512){
    float s, c; sincosf(-TWO_PI_F * (float)i * (1.f/1024.f), &s, &c);
    twg[i] = make_float2(c, s);
  }
}

// ---------------------------------------------------------------------------
// Spatial half: 32x32 tile/block, 4 px/thread, one dispatch.
// R17: algebraic cuts in the k-loop:
//  - accg = wa*(sd+dd+2cd), wa = w1+0.5(w2+w3)  (2w1+w2+w3 == 2*wa)
//  - rolling per-row sums: weighted row sums (1,2,1) for sobel-y/slope-y and
//    plain/square row sums for smooth, computed once per ROW (6 rows) instead
//    of once per 3x3 window (12 windows).
// ---------------------------------------------------------------------------
__global__ __launch_bounds__(256, 4)
void spatial_kernel(const float* __restrict__ pred, const float* __restrict__ targ,
                    const float* __restrict__ mask, double* __restrict__ acc){
  __shared__ v2f spt[36*44];               // (pred, targ) halo tile, stride 44
  __shared__ v2f pmt[34*35];               // union: smkf float[38*41] / (pmag,tmag)
  __shared__ unsigned long long mrow[38];
  __shared__ float sc[4];
  float* const smkf = (float*)pmt;         // 1558 floats = 6232 B <= 9520 B

  const int tid = threadIdx.x;
  const int x0 = blockIdx.x << 5, y0 = blockIdx.y << 5;
  const int z = blockIdx.z;
  const size_t ib = (size_t)z * ((size_t)HW * HW);
  const bool interior = ((unsigned)(blockIdx.x - 1) < 30u) &&
                        ((unsigned)(blockIdx.y - 1) < 30u);

  if (interior){
    const float* pb = pred + ib;
    const float* tb = targ + ib;
    for (int i = tid; i < 360; i += 256){        // 36 rows x 10 float4 (40 cols)
      int a = i / 10, b = i % 10;
      size_t off = (size_t)(y0 - 2 + a) * HW + (x0 - 4 + 4*b);
      float4 pv = *(const float4*)(pb + off);
      float4 tv = *(const float4*)(tb + off);
      int o = a*44 + 4*b;
      spt[o+0] = mkv2(pv.x, tv.x);
      spt[o+1] = mkv2(pv.y, tv.y);
      spt[o+2] = mkv2(pv.z, tv.z);
      spt[o+3] = mkv2(pv.w, tv.w);
    }
    const float* mb = mask + ib;
    for (int i = tid; i < 380; i += 256){        // 38 rows x 10 float4
      int a = i / 10, b = i % 10;
      size_t off = (size_t)(y0 - 3 + a) * HW + (x0 - 4 + 4*b);
      float4 v = *(const float4*)(mb + off);
      int o = a*41 + 4*b;
      smkf[o]=v.x; smkf[o+1]=v.y; smkf[o+2]=v.z; smkf[o+3]=v.w;
    }
  } else {
    for (int i = tid; i < 1296; i += 256){
      int a = i / 36, b = i % 36;
      int gy = y0 - 2 + a, gx = x0 - 2 + b;
      float pv = 0.f, tv = 0.f;
      if ((unsigned)gy < HW && (unsigned)gx < HW){
        size_t idx = ib + (size_t)gy * HW + gx;
        pv = pred[idx]; tv = targ[idx];
      }
      spt[a*44 + b + 2] = mkv2(pv, tv);
    }
    for (int i = tid; i < 1444; i += 256){
      int a = i / 38, b = i % 38;
      int gy = y0 - 3 + a, gx = x0 - 3 + b;
      float v = 0.f;
      if ((unsigned)gy < HW && (unsigned)gx < HW) v = mask[ib + (size_t)gy * HW + gx];
      smkf[a*41 + b + 1] = v;
    }
  }
  __syncthreads();

  unsigned long long mw = 0ull;
  if (tid < 38){
    #pragma unroll
    for (int x = 0; x < 38; x++)
      mw |= (smkf[tid*41 + 1 + x] > 0.5f) ? (1ull << x) : 0ull;
  }
  __syncthreads();                              // smkf reads done; pmt reuse ok
  if (tid < 38) mrow[tid] = mw;

  if (interior){
    for (int i = tid; i < 1156; i += 256){      // no bounds checks: always in-range
      int iy = i / 34, ix = i % 34;
      int o = iy*44 + ix + 2;
      v2f a00=spt[o],    a01=spt[o+1],  a02=spt[o+2];
      v2f a10=spt[o+44],                a12=spt[o+46];
      v2f a20=spt[o+88], a21=spt[o+89], a22=spt[o+90];
      v2f gx = (a02 + v2s(2.f)*a12 + a22) - (a00 + v2s(2.f)*a10 + a20);
      v2f gy = (a20 + v2s(2.f)*a21 + a22) - (a00 + v2s(2.f)*a01 + a02);
      v2f m2 = gx*gx + gy*gy + v2s(1e-8f);
      pmt[iy*35+ix] = mkv2(fsqrt(m2.x), fsqrt(m2.y));
    }
  } else {
    for (int i = tid; i < 1156; i += 256){
      int iy = i / 34, ix = i % 34;
      int gy = y0 - 1 + iy, gx = x0 - 1 + ix;
      v2f out = v2s(0.f);
      if ((unsigned)gy < HW && (unsigned)gx < HW){
        int o = iy*44 + ix + 2;
        v2f a00=spt[o],    a01=spt[o+1],  a02=spt[o+2];
        v2f a10=spt[o+44],                a12=spt[o+46];
        v2f a20=spt[o+88], a21=spt[o+89], a22=spt[o+90];
        v2f gxv = (a02 + v2s(2.f)*a12 + a22) - (a00 + v2s(2.f)*a10 + a20);
        v2f gyv = (a20 + v2s(2.f)*a21 + a22) - (a00 + v2s(2.f)*a01 + a02);
        v2f m2 = gxv*gxv + gyv*gyv + v2s(1e-8f);
        out = mkv2(fsqrt(m2.x), fsqrt(m2.y));
      }
      pmt[iy*35+ix] = out;
    }
  }
  __syncthreads();

  const int ty = tid >> 5, tx = tid & 31;
  const int r0 = ty << 2;

  // packed counts: cp[j] = c1 | c2<<8 | c3<<16 (vertical sums can't carry)
  int cp[10];
  #pragma unroll
  for (int j = 0; j < 10; j++){
    unsigned w = (unsigned)(mrow[r0 + j] >> tx);
    int c3 = __popc(w & 0x7Fu);
    int c2 = __popc((w >> 1) & 0x1Fu);
    int c1 = __popc((w >> 2) & 0x7u);
    cp[j] = c1 | (c2 << 8) | (c3 << 16);
  }

  v2f PQ[3][3], AB[3][3];
  #pragma unroll
  for (int rr = 0; rr < 2; rr++)
    #pragma unroll
    for (int cc = 0; cc < 3; cc++){
      PQ[rr][cc] = spt[(r0+1+rr)*44 + tx+3+cc];
      AB[rr][cc] = pmt[(r0+rr)*35 + tx+cc];
    }

  // per-row rolling state: slot r <-> PQ row (r0+1+r) / AB row (r0+r)
  v2f wR[6], wA[6];      // (1,2,1)-weighted row sums (sobel-y / slope-y)
  float uR[6], qR[6];    // plain and squared row sums of pred (smooth)
  #pragma unroll
  for (int r = 0; r < 2; r++){
    wR[r] = PQ[r][0] + v2s(2.f)*PQ[r][1] + PQ[r][2];
    float p0 = PQ[r][0].x, p1 = PQ[r][1].x, p2 = PQ[r][2].x;
    uR[r] = p0 + p1 + p2;
    qR[r] = fmaf(p0, p0, fmaf(p1, p1, p2*p2));
    wA[r] = AB[r][0] + v2s(2.f)*AB[r][1] + AB[r][2];
  }

  float accg = 0.f, accs = 0.f, accl = 0.f;
  #pragma unroll
  for (int k = 0; k < 4; k++){
    // load the new bottom rows (PQ row r0+k+3, AB row r0+k+2)
    #pragma unroll
    for (int cc = 0; cc < 3; cc++){
      PQ[2][cc] = spt[(r0+k+3)*44 + tx+3+cc];
      AB[2][cc] = pmt[(r0+k+2)*35 + tx+cc];
    }
    {
      wR[k+2] = PQ[2][0] + v2s(2.f)*PQ[2][1] + PQ[2][2];
      float p0 = PQ[2][0].x, p1 = PQ[2][1].x, p2 = PQ[2][2].x;
      uR[k+2] = p0 + p1 + p2;
      qR[k+2] = fmaf(p0, p0, fmaf(p1, p1, p2*p2));
      wA[k+2] = AB[2][0] + v2s(2.f)*AB[2][1] + AB[2][2];
    }

    v2f gxv = (PQ[0][2] + v2s(2.f)*PQ[1][2] + PQ[2][2]) - (PQ[0][0] + v2s(2.f)*PQ[1][0] + PQ[2][0]);
    v2f gyv = wR[k+2] - wR[k];
    v2f cvv = v2s(4.f)*PQ[1][1] - PQ[0][1] - PQ[1][0] - PQ[1][2] - PQ[2][1];

    float sd = fabsf(AB[1][1].x - AB[1][1].y);
    float x1 = gxv.x + 1e-8f, y1 = gyv.x;
    float x2 = gxv.y + 1e-8f, y2 = gyv.y;
    float dd = fast_atan2_abs(fabsf(y1*x2 - x1*y2), x1*x2 + y1*y2);
    float cd = fabsf(cvv.x - cvv.y);

    int s1p = cp[k+2] + cp[k+3] + cp[k+4];
    int s2p = s1p + cp[k+1] + cp[k+5];
    int s3p = s2p + cp[k]   + cp[k+6];
    int s1 = s1p & 0xFF;
    int s2 = (s2p >> 8) & 0xFF;
    int s3 = s3p >> 16;
    float w1 = ((unsigned)(s1 - 1) <  8u) ? 1.f : 0.f;
    float w2 = ((unsigned)(s2 - 1) < 24u) ? 1.f : 0.f;
    float w3 = ((unsigned)(s3 - 1) < 48u) ? 1.f : 0.f;
    float wa = fmaf(0.5f, w2 + w3, w1);

    accg = fmaf(wa, sd + dd + 2.f*cd, accg);

    float s9 = uR[k] + uR[k+1] + uR[k+2];
    float s9q = qR[k] + qR[k+1] + qR[k+2];
    float lm = s9 * (1.f/9.f), lq = s9q * (1.f/9.f);
    accs = fmaf(fsqrt(fmaxf(lq - lm*lm, 1e-8f)), w1, accs);

    v2f px = (AB[0][2] + v2s(2.f)*AB[1][2] + AB[2][2]) - (AB[0][0] + v2s(2.f)*AB[1][0] + AB[2][0]);
    v2f py = wA[k+2] - wA[k];
    v2f ch2 = px*px + py*py + v2s(1e-8f);
    accl = fmaf(fabsf(fsqrt(ch2.x) - fsqrt(ch2.y)), w1, accl);

    if (k < 3){
      #pragma unroll
      for (int cc = 0; cc < 3; cc++){
        PQ[0][cc] = PQ[1][cc]; PQ[1][cc] = PQ[2][cc];
        AB[0][cc] = AB[1][cc]; AB[1][cc] = AB[2][cc];
      }
    }
  }

  float g  = block_reduce_add_f(accg, sc);
  float sm = block_reduce_add_f(accs, sc);
  float sl = block_reduce_add_f(accl, sc);
  if (tid == 0){
    int slot = (blockIdx.x + blockIdx.y * 7 + z * 13) & (NSLOT - 1);
    atomicAdd(&acc[0*NSLOT + slot], (double)g);
    atomicAdd(&acc[1*NSLOT + slot], (double)sm);
    atomicAdd(&acc[2*NSLOT + slot], (double)sl);
  }
}

// ---------------------------------------------------------------------------
// Lane-xor exchange: DPP for h=1,2,8 (0x128 = ROW_ROR:8 == xor8 within row);
// ds_swizzle h=4,16 (no DPP encoding for xor4/xor16);
// h=32 via v_permlane32_swap_b32 (VALU).
// ---------------------------------------------------------------------------
__device__ __forceinline__ float lane_xor(float x, int h, int lane){
  int xi = __float_as_int(x);
  int r;
  if (h == 1)       r = __builtin_amdgcn_update_dpp(xi, xi, 0xB1, 0xF, 0xF, true);
  else if (h == 2)  r = __builtin_amdgcn_update_dpp(xi, xi, 0x4E, 0xF, 0xF, true);
  else if (h == 8)  r = __builtin_amdgcn_update_dpp(xi, xi, 0x128, 0xF, 0xF, true);
  else if (h == 4)  r = __builtin_amdgcn_ds_swizzle(xi, 0x101F);  // xor4
  else if (h == 16) r = __builtin_amdgcn_ds_swizzle(xi, 0x401F);  // xor16
  else {
    i2v pr = __builtin_amdgcn_permlane32_swap(xi, xi, false, false);
    r = (lane & 32) ? pr.x : pr.y;   // x: lanes>=32 got partner; y: lanes<32
  }
  return __int_as_float(r);
}

// ---------------------------------------------------------------------------
// Wave-level 1024-pt FFT: 64 (cross-lane) x 16 (in-register).
// Twiddle-before-exchange butterfly: t = w_eff * v, exchange t,
// result = fma(sgn, t, partner_t). 8 VALU/butterfly. Log-depth power ladder.
// ---------------------------------------------------------------------------
#define FC 0.70710678118654752f
#define FC1 0.92387953251128676f
#define FS1 0.38268343236508977f

__device__ __forceinline__ void bfly(float2& a, float2& b){
  float tx = b.x, ty = b.y;
  b.x = a.x - tx; b.y = a.y - ty;
  a.x += tx;      a.y += ty;
}
__device__ __forceinline__ void cmul_c(float2& b, float wr, float wi){
  float tx = wr*b.x - wi*b.y, ty = wr*b.y + wi*b.x;
  b.x = tx; b.y = ty;
}
__device__ __forceinline__ void rotmi(float2& b){   // b *= -i
  float t = b.x; b.x = b.y; b.y = -t;
}

__device__ __forceinline__ void fft16_reg(float2* v){
  float2 y[16];
  y[0]=v[0];  y[1]=v[8];  y[2]=v[4];  y[3]=v[12];
  y[4]=v[2];  y[5]=v[10]; y[6]=v[6];  y[7]=v[14];
  y[8]=v[1];  y[9]=v[9];  y[10]=v[5]; y[11]=v[13];
  y[12]=v[3]; y[13]=v[11];y[14]=v[7]; y[15]=v[15];
  #pragma unroll
  for (int g = 0; g < 8; g++) bfly(y[2*g], y[2*g+1]);
  #pragma unroll
  for (int g = 0; g < 4; g++){
    int b = 4*g;
    bfly(y[b], y[b+2]);
    rotmi(y[b+3]); bfly(y[b+1], y[b+3]);
  }
  #pragma unroll
  for (int g = 0; g < 2; g++){
    int b = 8*g;
    bfly(y[b], y[b+4]);
    cmul_c(y[b+5],  FC, -FC); bfly(y[b+1], y[b+5]);
    rotmi(y[b+6]);            bfly(y[b+2], y[b+6]);
    cmul_c(y[b+7], -FC, -FC); bfly(y[b+3], y[b+7]);
  }
  bfly(y[0], y[8]);
  cmul_c(y[9],   FC1, -FS1); bfly(y[1], y[9]);
  cmul_c(y[10],  FC,  -FC);  bfly(y[2], y[10]);
  cmul_c(y[11],  FS1, -FC1); bfly(y[3], y[11]);
  rotmi(y[12]);              bfly(y[4], y[12]);
  cmul_c(y[13], -FS1, -FC1); bfly(y[5], y[13]);
  cmul_c(y[14], -FC,  -FC);  bfly(y[6], y[14]);
  cmul_c(y[15], -FC1, -FS1); bfly(y[7], y[15]);
  #pragma unroll
  for (int j = 0; j < 16; j++) v[j] = y[j];
}

__device__ __forceinline__ void fft1024_wave(float2* v, int lane,
                                             const float2* __restrict__ twg){
  // stage 0 (w = 1 for all lanes): t = v; exchange; v = partner_t + sgn*t
  {
    const float sgn = (lane & 1) ? -1.f : 1.f;
    #pragma unroll
    for (int j = 0; j < 16; j++){
      float ox = lane_xor(v[j].x, 1, lane);
      float oy = lane_xor(v[j].y, 1, lane);
      v[j].x = fmaf(sgn, v[j].x, ox);
      v[j].y = fmaf(sgn, v[j].y, oy);
    }
  }
  #pragma unroll
  for (int s = 1; s < 6; s++){
    const int h = 1 << s;
    const bool up = (lane & h) != 0;
    const float2 w = twg[(lane & (h - 1)) << (9 - s)];
    const float ewx = up ? w.x : 1.f;
    const float ewy = up ? w.y : 0.f;
    const float sgn = up ? -1.f : 1.f;
    #pragma unroll
    for (int j = 0; j < 16; j++){
      float tx = ewx*v[j].x - ewy*v[j].y;
      float ty = ewx*v[j].y + ewy*v[j].x;
      float ox = lane_xor(tx, h, lane);
      float oy = lane_xor(ty, h, lane);
      v[j].x = fmaf(sgn, tx, ox);
      v[j].y = fmaf(sgn, ty, oy);
    }
  }
  // per-slot twiddle: v[j] *= w^j, w = twg[lane]; log-depth powers
  float2 w1 = twg[lane];
  float2 w2 = cmulf(w1, w1);
  float2 w3 = cmulf(w2, w1);
  float2 w4 = cmulf(w2, w2);
  float2 w5 = cmulf(w3, w2);
  float2 w6 = cmulf(w3, w3);
  float2 w7 = cmulf(w4, w3);
  float2 w8 = cmulf(w4, w4);
  v[1]  = cmulf(v[1],  w1);
  v[2]  = cmulf(v[2],  w2);
  v[3]  = cmulf(v[3],  w3);
  v[4]  = cmulf(v[4],  w4);
  v[5]  = cmulf(v[5],  w5);
  v[6]  = cmulf(v[6],  w6);
  v[7]  = cmulf(v[7],  w7);
  v[8]  = cmulf(v[8],  w8);
  v[9]  = cmulf(cmulf(v[9],  w8), w1);
  v[10] = cmulf(cmulf(v[10], w8), w2);
  v[11] = cmulf(cmulf(v[11], w8), w3);
  v[12] = cmulf(cmulf(v[12], w8), w4);
  v[13] = cmulf(cmulf(v[13], w8), w5);
  v[14] = cmulf(cmulf(v[14], w8), w6);
  v[15] = cmulf(cmulf(v[15], w8), w7);
  fft16_reg(v);
}

// ---------------------------------------------------------------------------
// FFT pass 1 + tiled transpose: Zt layout [y>>3][k][y&7] (fp32 float2).
// 2-phase transpose (tile[8]) -> 4 barriers.
// R17: __launch_bounds__(512, 2) — allow the scheduler to trade occupancy for
// registers (VGPR cap 256). fft1024_wave needs ~100 live VGPRs; if the default
// heuristic targeted 8 waves/EU (64 VGPR) it was spilling to scratch.
// ---------------------------------------------------------------------------
__global__ __launch_bounds__(512, 2)
void fft_rows_t_kernel(const float* __restrict__ pred, const float* __restrict__ targ,
                       float2* __restrict__ Zt, const float2* __restrict__ twg){
  __shared__ float2 tile[8][64][9];
  const int tid = threadIdx.x;
  const int lane = tid & 63;
  const int w = tid >> 6;
  const int y0 = blockIdx.x << 3;
  const size_t ibase = ((size_t)blockIdx.y * HW + (y0 + w)) * HW;
  const int rb = __brev(lane) >> 26;
  const float4* p4 = (const float4*)(pred + ibase);
  const float4* t4 = (const float4*)(targ + ibase);
  float2 v[16];
  #pragma unroll
  for (int m = 0; m < 4; m++){
    float4 a = p4[4*rb + m];
    float4 b = t4[4*rb + m];
    v[4*m+0] = make_float2(a.x, b.x);
    v[4*m+1] = make_float2(a.y, b.y);
    v[4*m+2] = make_float2(a.z, b.z);
    v[4*m+3] = make_float2(a.w, b.w);
  }
  fft1024_wave(v, lane, twg);
  float2* zb = Zt + (size_t)blockIdx.y * HW * HW + (size_t)blockIdx.x * 8192;
  const int yl = tid & 7, kl = tid >> 3;
  #pragma unroll
  for (int jb = 0; jb < 2; jb++){
    __syncthreads();
    #pragma unroll
    for (int jj = 0; jj < 8; jj++) tile[jj][lane][w] = v[8*jb + jj];
    __syncthreads();
    #pragma unroll
    for (int jj = 0; jj < 8; jj++){
      int k = ((jb << 3) + jj) * 64 + kl;
      zb[k * 8 + yl] = tile[jj][kl][yl];     // contiguous across the block
    }
  }
}

// ---------------------------------------------------------------------------
// FFT pass 2 + reduce: one FFT per wave, Hermitian partner via natural-order
// LDS. Reads the tiled Zt: lane's 16-y chunk = two 64-B contiguous segments.
// R17: __launch_bounds__(256, 2) — same register-release rationale as rows.
// ---------------------------------------------------------------------------
__device__ __forceinline__ void freq_contrib(float2 Zk, float2 Zm, int k1, int k2,
                                             float& ms, float& ps){
  int di = k1 - 512, dj = k2 - 512;
  if (di*di + dj*dj < 94372) return;         // dist > 307.2  <=>  r2 >= 94372
  float pr = 0.5f*(Zk.x + Zm.x);
  float pi = 0.5f*(Zk.y - Zm.y);
  float tr = 0.5f*(Zk.y + Zm.y);
  float ti = 0.5f*(Zm.x - Zk.x);
  float p2 = pr*pr + pi*pi;
  float t2 = tr*tr + ti*ti;
  ms += p2 + t2 - 2.f*fsqrt(p2*t2);
  float re = pr*tr + pi*ti;
  float im = pi*tr - pr*ti;
  float pd = fast_atan2_abs(fabsf(im), re);  // squared below; sign irrelevant
  ps += pd*pd;
}

__global__ __launch_bounds__(256, 2)
void fft_cols2_kernel(const float2* __restrict__ Z, const float2* __restrict__ twg,
                      double* __restrict__ acc){
  __shared__ float2 ex[4][1024];            // per-wave natural-order spectrum
  const int lane = threadIdx.x & 63;
  const int w = threadIdx.x >> 6;           // 0..3
  const int p = 2 * blockIdx.x + (w >> 1);  // pair index, 0..512 valid
  const bool valid = (p <= 512);
  const int r = (w & 1) ? ((1024 - p) & 1023) : p;   // this wave's Zt row (k)
  const float2* base = Z + (size_t)blockIdx.y * HW * HW;
  const int rb = __brev(lane) >> 26;

  float2 v[16];
  if (valid){
    const float4* f4 = (const float4*)base;
    #pragma unroll
    for (int s = 0; s < 2; s++){
      size_t o = (size_t)(2*rb + s) * 4096 + (size_t)r * 4;  // float4 units
      #pragma unroll
      for (int q = 0; q < 4; q++){
        float4 x = f4[o + q];
        v[8*s + 2*q]     = make_float2(x.x, x.y);
        v[8*s + 2*q + 1] = make_float2(x.z, x.w);
      }
    }
    fft1024_wave(v, lane, twg);
    #pragma unroll
    for (int j = 0; j < 16; j++) ex[w][lane + (j << 6)] = v[j];
  }
  __syncthreads();
  if (!valid) return;
  const bool self = (p == 0) || (p == 512);
  if ((w & 1) && self) return;              // duplicate row: LDS written, no contribs

  const float2* pb = ex[w ^ 1];             // partner spectrum, natural order
  float ms = 0.f, ps = 0.f;
  #pragma unroll
  for (int j = 0; j < 16; j++){
    int k = lane + (j << 6);
    float2 zm = pb[(1024 - k) & 1023];      // Z_partner(-k)
    freq_contrib(v[j], zm, k, r, ms, ps);
  }
  #pragma unroll
  for (int o = 32; o > 0; o >>= 1){
    ms += __shfl_down(ms, o, 64);
    ps += __shfl_down(ps, o, 64);
  }
  if (lane == 0){
    int slot = (r + blockIdx.y * 11) & (NSLOT - 1);
    atomicAdd(&acc[3*NSLOT + slot], (double)ms);
    atomicAdd(&acc[4*NSLOT + slot], (double)ps);
  }
}

// ---------------------------------------------------------------------------
__global__ void finalize_kernel(const double* __restrict__ acc, float* __restrict__ out){
  const int t = threadIdx.x;   // 64 threads
  double v[5];
  #pragma unroll
  for (int s = 0; s < 5; s++) v[s] = acc[s*NSLOT + t];
  #pragma unroll
  for (int o = 32; o > 0; o >>= 1)
    #pragma unroll
    for (int s = 0; s < 5; s++) v[s] += __shfl_down(v[s], o, 64);
  if (t == 0){
    const double inv = 1.0 / 8388608.0;      // mean over 8*1024*1024
    double grad   = v[0] * inv / 3.0;        // / len(bms)
    double smooth = v[1] * inv;
    double slope  = v[2] * inv;
    double freq   = (v[3] + 2.0 * v[4]) * inv;
    double total  = 2.0*grad + 1.5*freq + 3.0*smooth + 2.0*slope;
    out[0] = (float)total;
    out[1] = (float)grad;
    out[2] = (float)freq;
    out[3] = (float)smooth;
    out[4] = (float)slope;
  }
}

extern "C" void kernel_launch(void* const* d_in, const int* in_sizes, int n_in,
                              void* d_out, int out_size, void* d_ws, size_t ws_size,
                              hipStream_t stream){
  const float* pred = (const float*)d_in[0];
  const float* targ = (const float*)d_in[1];
  const float* mask = (const float*)d_in[2];
  double* acc  = (double*)d_ws;                         // [0, 2560)
  float2* twg  = (float2*)((char*)d_ws + 4096);         // [4096, 8192)
  float2* Z    = (float2*)((char*)d_ws + 8192);         // 8 x 8 MiB fp32 images
  // ws_size ~256 MiB (measured R9) — 64 MiB Z fits with margin.

  setup_kernel<<<2, 256, 0, stream>>>(acc, twg);
  spatial_kernel<<<dim3(32, 32, 8), 256, 0, stream>>>(pred, targ, mask, acc);
  fft_rows_t_kernel<<<dim3(128, 8), 512, 0, stream>>>(pred, targ, Z, twg);
  fft_cols2_kernel<<<dim3(257, 8), 256, 0, stream>>>(Z, twg, acc);
  finalize_kernel<<<1, 64, 0, stream>>>(acc, (float*)d_out);
}

// Round 7
// 225.133 us; speedup vs baseline: 1.1808x; 1.0028x over previous
//
#include <hip/hip_runtime.h>

#define HW 1024
#define TWO_PI_F 6.28318530717958647692f
#define NSLOT 64   // atomic spreading: 64 slots per accumulator, 5 accumulators

typedef float v2f __attribute__((ext_vector_type(2)));
typedef int   i2v __attribute__((ext_vector_type(2)));

__device__ __forceinline__ v2f mkv2(float a, float b){ v2f r; r.x = a; r.y = b; return r; }
__device__ __forceinline__ v2f v2s(float s){ v2f r; r.x = s; r.y = s; return r; }

__device__ __forceinline__ float2 cmulf(float2 a, float2 b){
  return make_float2(a.x*b.x - a.y*b.y, a.x*b.y + a.y*b.x);
}
__device__ __forceinline__ float fsqrt(float x){ return __builtin_amdgcn_sqrtf(x); }

// fast |atan2|: caller passes ay = |y| >= 0. Saves the final sign-select.
__device__ __forceinline__ float fast_atan2_abs(float ay, float x){
  float ax = fabsf(x);
  float mx = fmaxf(ax, ay), mn = fminf(ax, ay);
  float a  = mn * __builtin_amdgcn_rcpf(fmaxf(mx, 1e-37f));
  float s  = a * a;
  float r  = ((((0.0208351f*s - 0.085133f)*s + 0.180141f)*s - 0.3302995f)*s
              + 0.999866f) * a;
  r = (ay > ax) ? 1.57079632679f - r : r;
  return (x < 0.f) ? 3.14159265359f - r : r;
}

// 256-thread block reduction (4 waves of 64), float
__device__ __forceinline__ float block_reduce_add_f(float v, float* sc){
  int tid = threadIdx.x;
  #pragma unroll
  for (int o = 32; o > 0; o >>= 1) v += __shfl_down(v, o, 64);
  __syncthreads();
  if ((tid & 63) == 0) sc[tid >> 6] = v;
  __syncthreads();
  return sc[0] + sc[1] + sc[2] + sc[3];
}

// merged setup: zero accumulators + twiddle table (one launch)
__global__ void setup_kernel(double* acc, float2* twg){
  int i = threadIdx.x + blockIdx.x * 256;   // grid 2 x 256 -> 0..511
  if (i < 5 * NSLOT) acc[i] = 0.0;
  if (i < 512){
    float s, c; sincosf(-TWO_PI_F * (float)i * (1.f/1024.f), &s, &c);
    twg[i] = make_float2(c, s);
  }
}

// ---------------------------------------------------------------------------
// Spatial half (R17 structure): 32x32 tile/block, 4 px/thread.
// ---------------------------------------------------------------------------
__global__ __launch_bounds__(256, 4)
void spatial_kernel(const float* __restrict__ pred, const float* __restrict__ targ,
                    const float* __restrict__ mask, double* __restrict__ acc){
  __shared__ v2f spt[36*44];               // (pred, targ) halo tile, stride 44
  __shared__ v2f pmt[34*35];               // union: smkf float[38*41] / (pmag,tmag)
  __shared__ unsigned long long mrow[38];
  __shared__ float sc[4];
  float* const smkf = (float*)pmt;         // 1558 floats = 6232 B <= 9520 B

  const int tid = threadIdx.x;
  const int x0 = blockIdx.x << 5, y0 = blockIdx.y << 5;
  const int z = blockIdx.z;
  const size_t ib = (size_t)z * ((size_t)HW * HW);
  const bool interior = ((unsigned)(blockIdx.x - 1) < 30u) &&
                        ((unsigned)(blockIdx.y - 1) < 30u);

  if (interior){
    const float* pb = pred + ib;
    const float* tb = targ + ib;
    for (int i = tid; i < 360; i += 256){        // 36 rows x 10 float4 (40 cols)
      int a = i / 10, b = i % 10;
      size_t off = (size_t)(y0 - 2 + a) * HW + (x0 - 4 + 4*b);
      float4 pv = *(const float4*)(pb + off);
      float4 tv = *(const float4*)(tb + off);
      int o = a*44 + 4*b;
      spt[o+0] = mkv2(pv.x, tv.x);
      spt[o+1] = mkv2(pv.y, tv.y);
      spt[o+2] = mkv2(pv.z, tv.z);
      spt[o+3] = mkv2(pv.w, tv.w);
    }
    const float* mb = mask + ib;
    for (int i = tid; i < 380; i += 256){        // 38 rows x 10 float4
      int a = i / 10, b = i % 10;
      size_t off = (size_t)(y0 - 3 + a) * HW + (x0 - 4 + 4*b);
      float4 v = *(const float4*)(mb + off);
      int o = a*41 + 4*b;
      smkf[o]=v.x; smkf[o+1]=v.y; smkf[o+2]=v.z; smkf[o+3]=v.w;
    }
  } else {
    for (int i = tid; i < 1296; i += 256){
      int a = i / 36, b = i % 36;
      int gy = y0 - 2 + a, gx = x0 - 2 + b;
      float pv = 0.f, tv = 0.f;
      if ((unsigned)gy < HW && (unsigned)gx < HW){
        size_t idx = ib + (size_t)gy * HW + gx;
        pv = pred[idx]; tv = targ[idx];
      }
      spt[a*44 + b + 2] = mkv2(pv, tv);
    }
    for (int i = tid; i < 1444; i += 256){
      int a = i / 38, b = i % 38;
      int gy = y0 - 3 + a, gx = x0 - 3 + b;
      float v = 0.f;
      if ((unsigned)gy < HW && (unsigned)gx < HW) v = mask[ib + (size_t)gy * HW + gx];
      smkf[a*41 + b + 1] = v;
    }
  }
  __syncthreads();

  unsigned long long mw = 0ull;
  if (tid < 38){
    #pragma unroll
    for (int x = 0; x < 38; x++)
      mw |= (smkf[tid*41 + 1 + x] > 0.5f) ? (1ull << x) : 0ull;
  }
  __syncthreads();                              // smkf reads done; pmt reuse ok
  if (tid < 38) mrow[tid] = mw;

  if (interior){
    for (int i = tid; i < 1156; i += 256){      // no bounds checks: always in-range
      int iy = i / 34, ix = i % 34;
      int o = iy*44 + ix + 2;
      v2f a00=spt[o],    a01=spt[o+1],  a02=spt[o+2];
      v2f a10=spt[o+44],                a12=spt[o+46];
      v2f a20=spt[o+88], a21=spt[o+89], a22=spt[o+90];
      v2f gx = (a02 + v2s(2.f)*a12 + a22) - (a00 + v2s(2.f)*a10 + a20);
      v2f gy = (a20 + v2s(2.f)*a21 + a22) - (a00 + v2s(2.f)*a01 + a02);
      v2f m2 = gx*gx + gy*gy + v2s(1e-8f);
      pmt[iy*35+ix] = mkv2(fsqrt(m2.x), fsqrt(m2.y));
    }
  } else {
    for (int i = tid; i < 1156; i += 256){
      int iy = i / 34, ix = i % 34;
      int gy = y0 - 1 + iy, gx = x0 - 1 + ix;
      v2f out = v2s(0.f);
      if ((unsigned)gy < HW && (unsigned)gx < HW){
        int o = iy*44 + ix + 2;
        v2f a00=spt[o],    a01=spt[o+1],  a02=spt[o+2];
        v2f a10=spt[o+44],                a12=spt[o+46];
        v2f a20=spt[o+88], a21=spt[o+89], a22=spt[o+90];
        v2f gxv = (a02 + v2s(2.f)*a12 + a22) - (a00 + v2s(2.f)*a10 + a20);
        v2f gyv = (a20 + v2s(2.f)*a21 + a22) - (a00 + v2s(2.f)*a01 + a02);
        v2f m2 = gxv*gxv + gyv*gyv + v2s(1e-8f);
        out = mkv2(fsqrt(m2.x), fsqrt(m2.y));
      }
      pmt[iy*35+ix] = out;
    }
  }
  __syncthreads();

  const int ty = tid >> 5, tx = tid & 31;
  const int r0 = ty << 2;

  // packed counts: cp[j] = c1 | c2<<8 | c3<<16 (vertical sums can't carry)
  int cp[10];
  #pragma unroll
  for (int j = 0; j < 10; j++){
    unsigned w = (unsigned)(mrow[r0 + j] >> tx);
    int c3 = __popc(w & 0x7Fu);
    int c2 = __popc((w >> 1) & 0x1Fu);
    int c1 = __popc((w >> 2) & 0x7u);
    cp[j] = c1 | (c2 << 8) | (c3 << 16);
  }

  v2f PQ[3][3], AB[3][3];
  #pragma unroll
  for (int rr = 0; rr < 2; rr++)
    #pragma unroll
    for (int cc = 0; cc < 3; cc++){
      PQ[rr][cc] = spt[(r0+1+rr)*44 + tx+3+cc];
      AB[rr][cc] = pmt[(r0+rr)*35 + tx+cc];
    }

  // per-row rolling state: slot r <-> PQ row (r0+1+r) / AB row (r0+r)
  v2f wR[6], wA[6];      // (1,2,1)-weighted row sums (sobel-y / slope-y)
  float uR[6], qR[6];    // plain and squared row sums of pred (smooth)
  #pragma unroll
  for (int r = 0; r < 2; r++){
    wR[r] = PQ[r][0] + v2s(2.f)*PQ[r][1] + PQ[r][2];
    float p0 = PQ[r][0].x, p1 = PQ[r][1].x, p2 = PQ[r][2].x;
    uR[r] = p0 + p1 + p2;
    qR[r] = fmaf(p0, p0, fmaf(p1, p1, p2*p2));
    wA[r] = AB[r][0] + v2s(2.f)*AB[r][1] + AB[r][2];
  }

  float accg = 0.f, accs = 0.f, accl = 0.f;
  #pragma unroll
  for (int k = 0; k < 4; k++){
    // load the new bottom rows (PQ row r0+k+3, AB row r0+k+2)
    #pragma unroll
    for (int cc = 0; cc < 3; cc++){
      PQ[2][cc] = spt[(r0+k+3)*44 + tx+3+cc];
      AB[2][cc] = pmt[(r0+k+2)*35 + tx+cc];
    }
    {
      wR[k+2] = PQ[2][0] + v2s(2.f)*PQ[2][1] + PQ[2][2];
      float p0 = PQ[2][0].x, p1 = PQ[2][1].x, p2 = PQ[2][2].x;
      uR[k+2] = p0 + p1 + p2;
      qR[k+2] = fmaf(p0, p0, fmaf(p1, p1, p2*p2));
      wA[k+2] = AB[2][0] + v2s(2.f)*AB[2][1] + AB[2][2];
    }

    v2f gxv = (PQ[0][2] + v2s(2.f)*PQ[1][2] + PQ[2][2]) - (PQ[0][0] + v2s(2.f)*PQ[1][0] + PQ[2][0]);
    v2f gyv = wR[k+2] - wR[k];
    v2f cvv = v2s(4.f)*PQ[1][1] - PQ[0][1] - PQ[1][0] - PQ[1][2] - PQ[2][1];

    float sd = fabsf(AB[1][1].x - AB[1][1].y);
    float x1 = gxv.x + 1e-8f, y1 = gyv.x;
    float x2 = gxv.y + 1e-8f, y2 = gyv.y;
    float dd = fast_atan2_abs(fabsf(y1*x2 - x1*y2), x1*x2 + y1*y2);
    float cd = fabsf(cvv.x - cvv.y);

    int s1p = cp[k+2] + cp[k+3] + cp[k+4];
    int s2p = s1p + cp[k+1] + cp[k+5];
    int s3p = s2p + cp[k]   + cp[k+6];
    int s1 = s1p & 0xFF;
    int s2 = (s2p >> 8) & 0xFF;
    int s3 = s3p >> 16;
    float w1 = ((unsigned)(s1 - 1) <  8u) ? 1.f : 0.f;
    float w2 = ((unsigned)(s2 - 1) < 24u) ? 1.f : 0.f;
    float w3 = ((unsigned)(s3 - 1) < 48u) ? 1.f : 0.f;
    float wa = fmaf(0.5f, w2 + w3, w1);

    accg = fmaf(wa, sd + dd + 2.f*cd, accg);

    float s9 = uR[k] + uR[k+1] + uR[k+2];
    float s9q = qR[k] + qR[k+1] + qR[k+2];
    float lm = s9 * (1.f/9.f), lq = s9q * (1.f/9.f);
    accs = fmaf(fsqrt(fmaxf(lq - lm*lm, 1e-8f)), w1, accs);

    v2f px = (AB[0][2] + v2s(2.f)*AB[1][2] + AB[2][2]) - (AB[0][0] + v2s(2.f)*AB[1][0] + AB[2][0]);
    v2f py = wA[k+2] - wA[k];
    v2f ch2 = px*px + py*py + v2s(1e-8f);
    accl = fmaf(fabsf(fsqrt(ch2.x) - fsqrt(ch2.y)), w1, accl);

    if (k < 3){
      #pragma unroll
      for (int cc = 0; cc < 3; cc++){
        PQ[0][cc] = PQ[1][cc]; PQ[1][cc] = PQ[2][cc];
        AB[0][cc] = AB[1][cc]; AB[1][cc] = AB[2][cc];
      }
    }
  }

  float g  = block_reduce_add_f(accg, sc);
  float sm = block_reduce_add_f(accs, sc);
  float sl = block_reduce_add_f(accl, sc);
  if (tid == 0){
    int slot = (blockIdx.x + blockIdx.y * 7 + z * 13) & (NSLOT - 1);
    atomicAdd(&acc[0*NSLOT + slot], (double)g);
    atomicAdd(&acc[1*NSLOT + slot], (double)sm);
    atomicAdd(&acc[2*NSLOT + slot], (double)sl);
  }
}

// ---------------------------------------------------------------------------
// R20: ALL-VALU lane exchanges, bank masks corrected.
// Direction ground truth (GPUOpen wave-scan: `row_shr:4 bank_mask:0xe`):
//   ROW_SHR:N -> DST[i] = SRC[i-N] (low lanes invalid)
//   ROW_SHL:N -> DST[i] = SRC[i+N] (high lanes invalid)
// xor4: banks 0,2 need SRC[i+4] (SHL), banks 1,3 need SRC[i-4] (SHR).
// ---------------------------------------------------------------------------
template<int CTRL>
__device__ __forceinline__ float xordpp(float x){
  int xi = __float_as_int(x);
  return __int_as_float(__builtin_amdgcn_update_dpp(xi, xi, CTRL, 0xF, 0xF, true));
}
__device__ __forceinline__ float xor4v(float x){
  int xi = __float_as_int(x);
  int t1 = __builtin_amdgcn_update_dpp(xi, xi, 0x104, 0xF, 0x5, false); // SHL4 -> banks 0,2 = SRC[i+4]
  int t2 = __builtin_amdgcn_update_dpp(t1, xi, 0x114, 0xF, 0xA, false); // SHR4 -> banks 1,3 = SRC[i-4]
  return __int_as_float(t2);
}

#define FC 0.70710678118654752f
#define FC1 0.92387953251128676f
#define FS1 0.38268343236508977f

__device__ __forceinline__ void bfly(float2& a, float2& b){
  float tx = b.x, ty = b.y;
  b.x = a.x - tx; b.y = a.y - ty;
  a.x += tx;      a.y += ty;
}
__device__ __forceinline__ void cmul_c(float2& b, float wr, float wi){
  float tx = wr*b.x - wi*b.y, ty = wr*b.y + wi*b.x;
  b.x = tx; b.y = ty;
}
__device__ __forceinline__ void rotmi(float2& b){   // b *= -i
  float t = b.x; b.x = b.y; b.y = -t;
}

__device__ __forceinline__ void fft16_reg(float2* v){
  float2 y[16];
  y[0]=v[0];  y[1]=v[8];  y[2]=v[4];  y[3]=v[12];
  y[4]=v[2];  y[5]=v[10]; y[6]=v[6];  y[7]=v[14];
  y[8]=v[1];  y[9]=v[9];  y[10]=v[5]; y[11]=v[13];
  y[12]=v[3]; y[13]=v[11];y[14]=v[7]; y[15]=v[15];
  #pragma unroll
  for (int g = 0; g < 8; g++) bfly(y[2*g], y[2*g+1]);
  #pragma unroll
  for (int g = 0; g < 4; g++){
    int b = 4*g;
    bfly(y[b], y[b+2]);
    rotmi(y[b+3]); bfly(y[b+1], y[b+3]);
  }
  #pragma unroll
  for (int g = 0; g < 2; g++){
    int b = 8*g;
    bfly(y[b], y[b+4]);
    cmul_c(y[b+5],  FC, -FC); bfly(y[b+1], y[b+5]);
    rotmi(y[b+6]);            bfly(y[b+2], y[b+6]);
    cmul_c(y[b+7], -FC, -FC); bfly(y[b+3], y[b+7]);
  }
  bfly(y[0], y[8]);
  cmul_c(y[9],   FC1, -FS1); bfly(y[1], y[9]);
  cmul_c(y[10],  FC,  -FC);  bfly(y[2], y[10]);
  cmul_c(y[11],  FS1, -FC1); bfly(y[3], y[11]);
  rotmi(y[12]);              bfly(y[4], y[12]);
  cmul_c(y[13], -FS1, -FC1); bfly(y[5], y[13]);
  cmul_c(y[14], -FC,  -FC);  bfly(y[6], y[14]);
  cmul_c(y[15], -FC1, -FS1); bfly(y[7], y[15]);
  #pragma unroll
  for (int j = 0; j < 16; j++) v[j] = y[j];
}

__device__ __forceinline__ void fft1024_wave(float2* v, int lane,
                                             const float2* __restrict__ twg){
  // hoisted twiddles: all 6 loads issue up front (one vmcnt wait)
  const float2 tw1 = twg[(lane & 1) << 8];
  const float2 tw2 = twg[(lane & 3) << 7];
  const float2 tw3 = twg[(lane & 7) << 6];
  const float2 tw4 = twg[(lane & 15) << 5];
  const float2 tw5 = twg[(lane & 31) << 4];
  const float2 wq  = twg[lane];

  // stage 0 (h=1, w=1): quad_perm xor1
  {
    const float sgn = (lane & 1) ? -1.f : 1.f;
    #pragma unroll
    for (int j = 0; j < 16; j++){
      float ox = xordpp<0xB1>(v[j].x);
      float oy = xordpp<0xB1>(v[j].y);
      v[j].x = fmaf(sgn, v[j].x, ox);
      v[j].y = fmaf(sgn, v[j].y, oy);
    }
  }
  // stage 1 (h=2): quad_perm xor2
  {
    const bool up = (lane & 2) != 0;
    const float ewx = up ? tw1.x : 1.f, ewy = up ? tw1.y : 0.f;
    const float sgn = up ? -1.f : 1.f;
    #pragma unroll
    for (int j = 0; j < 16; j++){
      float tx = ewx*v[j].x - ewy*v[j].y;
      float ty = ewx*v[j].y + ewy*v[j].x;
      v[j].x = fmaf(sgn, tx, xordpp<0x4E>(tx));
      v[j].y = fmaf(sgn, ty, xordpp<0x4E>(ty));
    }
  }
  // stage 2 (h=4): two bank-masked DPPs
  {
    const bool up = (lane & 4) != 0;
    const float ewx = up ? tw2.x : 1.f, ewy = up ? tw2.y : 0.f;
    const float sgn = up ? -1.f : 1.f;
    #pragma unroll
    for (int j = 0; j < 16; j++){
      float tx = ewx*v[j].x - ewy*v[j].y;
      float ty = ewx*v[j].y + ewy*v[j].x;
      v[j].x = fmaf(sgn, tx, xor4v(tx));
      v[j].y = fmaf(sgn, ty, xor4v(ty));
    }
  }
  // stage 3 (h=8): ROW_ROR:8 == xor8 (symmetric: (i+8) mod 16 == i^8)
  {
    const bool up = (lane & 8) != 0;
    const float ewx = up ? tw3.x : 1.f, ewy = up ? tw3.y : 0.f;
    const float sgn = up ? -1.f : 1.f;
    #pragma unroll
    for (int j = 0; j < 16; j++){
      float tx = ewx*v[j].x - ewy*v[j].y;
      float ty = ewx*v[j].y + ewy*v[j].x;
      v[j].x = fmaf(sgn, tx, xordpp<0x128>(tx));
      v[j].y = fmaf(sgn, ty, xordpp<0x128>(ty));
    }
  }
  // stage 4 (h=16): permlane16_swap fused: even-row copy in .x, odd-row copy in .y
  {
    const bool up = (lane & 16) != 0;
    const float ewx = up ? tw4.x : 1.f, ewy = up ? tw4.y : 0.f;
    const float sgn = up ? -1.f : 1.f;
    #pragma unroll
    for (int j = 0; j < 16; j++){
      float tx = ewx*v[j].x - ewy*v[j].y;
      float ty = ewx*v[j].y + ewy*v[j].x;
      i2v px = __builtin_amdgcn_permlane16_swap(__float_as_int(tx), __float_as_int(tx), false, false);
      i2v py = __builtin_amdgcn_permlane16_swap(__float_as_int(ty), __float_as_int(ty), false, false);
      v[j].x = fmaf(sgn, __int_as_float(px.y), __int_as_float(px.x));
      v[j].y = fmaf(sgn, __int_as_float(py.y), __int_as_float(py.x));
    }
  }
  // stage 5 (h=32): permlane32_swap fused: low-half copy in .x, high-half in .y
  {
    const bool up = (lane & 32) != 0;
    const float ewx = up ? tw5.x : 1.f, ewy = up ? tw5.y : 0.f;
    const float sgn = up ? -1.f : 1.f;
    #pragma unroll
    for (int j = 0; j < 16; j++){
      float tx = ewx*v[j].x - ewy*v[j].y;
      float ty = ewx*v[j].y + ewy*v[j].x;
      i2v px = __builtin_amdgcn_permlane32_swap(__float_as_int(tx), __float_as_int(tx), false, false);
      i2v py = __builtin_amdgcn_permlane32_swap(__float_as_int(ty), __float_as_int(ty), false, false);
      v[j].x = fmaf(sgn, __int_as_float(px.y), __int_as_float(px.x));
      v[j].y = fmaf(sgn, __int_as_float(py.y), __int_as_float(py.x));
    }
  }
  // per-slot twiddle: v[j] *= wq^j; log-depth powers
  float2 w2 = cmulf(wq, wq);
  float2 w3 = cmulf(w2, wq);
  float2 w4 = cmulf(w2, w2);
  float2 w5 = cmulf(w3, w2);
  float2 w6 = cmulf(w3, w3);
  float2 w7 = cmulf(w4, w3);
  float2 w8 = cmulf(w4, w4);
  v[1]  = cmulf(v[1],  wq);
  v[2]  = cmulf(v[2],  w2);
  v[3]  = cmulf(v[3],  w3);
  v[4]  = cmulf(v[4],  w4);
  v[5]  = cmulf(v[5],  w5);
  v[6]  = cmulf(v[6],  w6);
  v[7]  = cmulf(v[7],  w7);
  v[8]  = cmulf(v[8],  w8);
  v[9]  = cmulf(cmulf(v[9],  w8), wq);
  v[10] = cmulf(cmulf(v[10], w8), w2);
  v[11] = cmulf(cmulf(v[11], w8), w3);
  v[12] = cmulf(cmulf(v[12], w8), w4);
  v[13] = cmulf(cmulf(v[13], w8), w5);
  v[14] = cmulf(cmulf(v[14], w8), w6);
  v[15] = cmulf(cmulf(v[15], w8), w7);
  fft16_reg(v);
}

// ---------------------------------------------------------------------------
// FFT pass 1 + tiled transpose: Zt layout [y>>3][k][y&7] (fp32 float2).
// 2-phase transpose (tile[8]) -> 4 barriers.
// ---------------------------------------------------------------------------
__global__ __launch_bounds__(512, 2)
void fft_rows_t_kernel(const float* __restrict__ pred, const float* __restrict__ targ,
                       float2* __restrict__ Zt, const float2* __restrict__ twg){
  __shared__ float2 tile[8][64][9];
  const int tid = threadIdx.x;
  const int lane = tid & 63;
  const int w = tid >> 6;
  const int y0 = blockIdx.x << 3;
  const size_t ibase = ((size_t)blockIdx.y * HW + (y0 + w)) * HW;
  const int rb = __brev(lane) >> 26;
  const float4* p4 = (const float4*)(pred + ibase);
  const float4* t4 = (const float4*)(targ + ibase);
  float2 v[16];
  #pragma unroll
  for (int m = 0; m < 4; m++){
    float4 a = p4[4*rb + m];
    float4 b = t4[4*rb + m];
    v[4*m+0] = make_float2(a.x, b.x);
    v[4*m+1] = make_float2(a.y, b.y);
    v[4*m+2] = make_float2(a.z, b.z);
    v[4*m+3] = make_float2(a.w, b.w);
  }
  fft1024_wave(v, lane, twg);
  float2* zb = Zt + (size_t)blockIdx.y * HW * HW + (size_t)blockIdx.x * 8192;
  const int yl = tid & 7, kl = tid >> 3;
  #pragma unroll
  for (int jb = 0; jb < 2; jb++){
    __syncthreads();
    #pragma unroll
    for (int jj = 0; jj < 8; jj++) tile[jj][lane][w] = v[8*jb + jj];
    __syncthreads();
    #pragma unroll
    for (int jj = 0; jj < 8; jj++){
      int k = ((jb << 3) + jj) * 64 + kl;
      zb[k * 8 + yl] = tile[jj][kl][yl];     // contiguous across the block
    }
  }
}

// ---------------------------------------------------------------------------
// FFT pass 2 + reduce: one FFT per wave, Hermitian partner via natural-order
// LDS. Reads the tiled Zt: lane's 16-y chunk = two 64-B contiguous segments.
// ---------------------------------------------------------------------------
__device__ __forceinline__ void freq_contrib(float2 Zk, float2 Zm, int k1, int k2,
                                             float& ms, float& ps){
  int di = k1 - 512, dj = k2 - 512;
  if (di*di + dj*dj < 94372) return;         // dist > 307.2  <=>  r2 >= 94372
  float pr = 0.5f*(Zk.x + Zm.x);
  float pi = 0.5f*(Zk.y - Zm.y);
  float tr = 0.5f*(Zk.y + Zm.y);
  float ti = 0.5f*(Zm.x - Zk.x);
  float p2 = pr*pr + pi*pi;
  float t2 = tr*tr + ti*ti;
  ms += p2 + t2 - 2.f*fsqrt(p2*t2);
  float re = pr*tr + pi*ti;
  float im = pi*tr - pr*ti;
  float pd = fast_atan2_abs(fabsf(im), re);  // squared below; sign irrelevant
  ps += pd*pd;
}

__global__ __launch_bounds__(256, 2)
void fft_cols2_kernel(const float2* __restrict__ Z, const float2* __restrict__ twg,
                      double* __restrict__ acc){
  __shared__ float2 ex[4][1024];            // per-wave natural-order spectrum
  const int lane = threadIdx.x & 63;
  const int w = threadIdx.x >> 6;           // 0..3
  const int p = 2 * blockIdx.x + (w >> 1);  // pair index, 0..512 valid
  const bool valid = (p <= 512);
  const int r = (w & 1) ? ((1024 - p) & 1023) : p;   // this wave's Zt row (k)
  const float2* base = Z + (size_t)blockIdx.y * HW * HW;
  const int rb = __brev(lane) >> 26;

  float2 v[16];
  if (valid){
    const float4* f4 = (const float4*)base;
    #pragma unroll
    for (int s = 0; s < 2; s++){
      size_t o = (size_t)(2*rb + s) * 4096 + (size_t)r * 4;  // float4 units
      #pragma unroll
      for (int q = 0; q < 4; q++){
        float4 x = f4[o + q];
        v[8*s + 2*q]     = make_float2(x.x, x.y);
        v[8*s + 2*q + 1] = make_float2(x.z, x.w);
      }
    }
    fft1024_wave(v, lane, twg);
    #pragma unroll
    for (int j = 0; j < 16; j++) ex[w][lane + (j << 6)] = v[j];
  }
  __syncthreads();
  if (!valid) return;
  const bool self = (p == 0) || (p == 512);
  if ((w & 1) && self) return;              // duplicate row: LDS written, no contribs

  const float2* pb = ex[w ^ 1];             // partner spectrum, natural order
  float ms = 0.f, ps = 0.f;
  #pragma unroll
  for (int j = 0; j < 16; j++){
    int k = lane + (j << 6);
    float2 zm = pb[(1024 - k) & 1023];      // Z_partner(-k)
    freq_contrib(v[j], zm, k, r, ms, ps);
  }
  #pragma unroll
  for (int o = 32; o > 0; o >>= 1){
    ms += __shfl_down(ms, o, 64);
    ps += __shfl_down(ps, o, 64);
  }
  if (lane == 0){
    int slot = (r + blockIdx.y * 11) & (NSLOT - 1);
    atomicAdd(&acc[3*NSLOT + slot], (double)ms);
    atomicAdd(&acc[4*NSLOT + slot], (double)ps);
  }
}

// ---------------------------------------------------------------------------
__global__ void finalize_kernel(const double* __restrict__ acc, float* __restrict__ out){
  const int t = threadIdx.x;   // 64 threads
  double v[5];
  #pragma unroll
  for (int s = 0; s < 5; s++) v[s] = acc[s*NSLOT + t];
  #pragma unroll
  for (int o = 32; o > 0; o >>= 1)
    #pragma unroll
    for (int s = 0; s < 5; s++) v[s] += __shfl_down(v[s], o, 64);
  if (t == 0){
    const double inv = 1.0 / 8388608.0;      // mean over 8*1024*1024
    double grad   = v[0] * inv / 3.0;        // / len(bms)
    double smooth = v[1] * inv;
    double slope  = v[2] * inv;
    double freq   = (v[3] + 2.0 * v[4]) * inv;
    double total  = 2.0*grad + 1.5*freq + 3.0*smooth + 2.0*slope;
    out[0] = (float)total;
    out[1] = (float)grad;
    out[2] = (float)freq;
    out[3] = (float)smooth;
    out[4] = (float)slope;
  }
}

extern "C" void kernel_launch(void* const* d_in, const int* in_sizes, int n_in,
                              void* d_out, int out_size, void* d_ws, size_t ws_size,
                              hipStream_t stream){
  const float* pred = (const float*)d_in[0];
  const float* targ = (const float*)d_in[1];
  const float* mask = (const float*)d_in[2];
  double* acc  = (double*)d_ws;                         // [0, 2560)
  float2* twg  = (float2*)((char*)d_ws + 4096);         // [4096, 8192)
  float2* Z    = (float2*)((char*)d_ws + 8192);         // 8 x 8 MiB fp32 images
  // ws_size ~256 MiB (measured R9) — 64 MiB Z fits with margin.

  setup_kernel<<<2, 256, 0, stream>>>(acc, twg);
  spatial_kernel<<<dim3(32, 32, 8), 256, 0, stream>>>(pred, targ, mask, acc);
  fft_rows_t_kernel<<<dim3(128, 8), 512, 0, stream>>>(pred, targ, Z, twg);
  fft_cols2_kernel<<<dim3(257, 8), 256, 0, stream>>>(Z, twg, acc);
  finalize_kernel<<<1, 64, 0, stream>>>(acc, (float*)d_out);
}